// Round 6
// baseline (1532.747 us; speedup 1.0000x reference)
//
#include <hip/hip_runtime.h>
#include <hip/hip_bf16.h>
#include <math.h>

#define NHEADS 4
#define DMODEL 512
#define HQK 128
#define HV 256
#define BBATCH 8
#define SH 56
#define SWW 56
#define SEQN (SH*SWW)          // 3136
#define NTOK (BBATCH*SEQN)     // 25088
#define CH2 32
#define NC2 (SEQN/CH2)         // 98

// sigma column permutation within each 128-col head: sigma(d) = (d&15)*8 + (d>>4).
// q/k/dbuf are stored sigma-permuted by k_prep; V, eb tables, dS stay natural.
// All MFMA d-contractions use sigma order on BOTH operands -> results equivalent.

typedef __bf16 bf16x8 __attribute__((ext_vector_type(8)));
typedef float  f32x4  __attribute__((ext_vector_type(4)));

__device__ __forceinline__ float silu_f(float v){ return v / (1.f + __expf(-v)); }

__device__ __forceinline__ float b2f(unsigned short u){
  union { unsigned int i; float f; } c; c.i = ((unsigned int)u) << 16; return c.f;
}
__device__ __forceinline__ unsigned short f2b(float f){
  __bf16 h = (__bf16)f;
  unsigned short u; __builtin_memcpy(&u, &h, 2); return u;
}
__device__ __forceinline__ float h2f(unsigned short u){
  _Float16 h; __builtin_memcpy(&h, &u, 2); return (float)h;
}
__device__ __forceinline__ unsigned short f2h(float f){
  _Float16 h = (_Float16)f; unsigned short u; __builtin_memcpy(&u, &h, 2); return u;
}
__device__ __forceinline__ float lsig16(float z){          // logsigmoid(z)/16
  float e = __expf(-fabsf(z));
  return (fminf(z, 0.f) - __logf(1.f + e)) * 0.0625f;
}
__device__ __forceinline__ void up8(uint4 v, unsigned short* o){
  o[0]=(unsigned short)v.x; o[1]=(unsigned short)(v.x>>16);
  o[2]=(unsigned short)v.y; o[3]=(unsigned short)(v.y>>16);
  o[4]=(unsigned short)v.z; o[5]=(unsigned short)(v.z>>16);
  o[6]=(unsigned short)v.w; o[7]=(unsigned short)(v.w>>16);
}
__device__ __forceinline__ uint4 pk8(const unsigned short* s){
  uint4 v;
  v.x = (unsigned)s[0] | ((unsigned)s[1]<<16);
  v.y = (unsigned)s[2] | ((unsigned)s[3]<<16);
  v.z = (unsigned)s[4] | ((unsigned)s[5]<<16);
  v.w = (unsigned)s[6] | ((unsigned)s[7]<<16);
  return v;
}

#define GLL16(gp, lp) __builtin_amdgcn_global_load_lds( \
    (const __attribute__((address_space(1))) unsigned int*)(gp), \
    (__attribute__((address_space(3))) unsigned int*)(lp), 16, 0, 0)

// ---------------- fp32 -> bf16 weight conversion ----------------
__global__ __launch_bounds__(256) void k_w2b(const float* __restrict__ w,
                                             unsigned short* __restrict__ o, int n){
  int i = (blockIdx.x*256 + threadIdx.x) << 2;
  if (i >= n) return;
  float4 v = *(const float4*)&w[i];
  ushort4 p;
  p.x = f2b(v.x); p.y = f2b(v.y); p.z = f2b(v.z); p.w = f2b(v.w);
  *(ushort4*)&o[i] = p;
}

// ---------------- Wc = gk_w2[1024,16] @ gk_w1[16,512] -> bf16 [1024][512] ----------------
__global__ __launch_bounds__(256) void k_wc(const float* __restrict__ w1,
                                            const float* __restrict__ w2,
                                            unsigned short* __restrict__ wc){
  int idx = blockIdx.x*256 + threadIdx.x;   // n*512 + k
  int n = idx >> 9, k = idx & 511;
  float acc = 0.f;
  #pragma unroll
  for (int r=0;r<16;++r) acc += w2[n*16+r]*w1[r*512+k];
  wc[idx] = f2b(acc);
}

// ---------------- conv 3x3 depthwise + SiLU -> xs (bf16) ----------------
__global__ __launch_bounds__(256) void k_conv_silu(const float* __restrict__ x,
                                                   const float* __restrict__ cw,
                                                   unsigned short* __restrict__ xs){
  int gid = blockIdx.x*256 + threadIdx.x;     // NTOK*128 threads
  int c4  = (gid & 127) << 2;
  int tok = gid >> 7;
  int b = tok / SEQN, sp = tok % SEQN;
  int hh = sp / SWW, ww = sp % SWW;
  float a0=0.f,a1=0.f,a2=0.f,a3=0.f;
  #pragma unroll
  for (int dh=-1; dh<=1; ++dh){
    int h2 = hh+dh; if (h2<0||h2>=SH) continue;
    #pragma unroll
    for (int dw=-1; dw<=1; ++dw){
      int w2 = ww+dw; if (w2<0||w2>=SWW) continue;
      const float4 xv = *(const float4*)&x[((size_t)(b*SEQN + h2*SWW + w2))*DMODEL + c4];
      int tap = (dh+1)*3 + (dw+1);
      a0 += xv.x * cw[(c4+0)*9 + tap];
      a1 += xv.y * cw[(c4+1)*9 + tap];
      a2 += xv.z * cw[(c4+2)*9 + tap];
      a3 += xv.w * cw[(c4+3)*9 + tap];
    }
  }
  ushort4 o;
  o.x = f2b(silu_f(a0)); o.y = f2b(silu_f(a1)); o.z = f2b(silu_f(a2)); o.w = f2b(silu_f(a3));
  *(ushort4*)&xs[(size_t)tok*DMODEL + c4] = o;
}

// ------- MFMA GEMM: C[M,N] = act(A_bf16[M,K] * W_bf16[N,K]^T + bias) -------
template<int ACT, int CBF>
__global__ __launch_bounds__(256) void k_gemm_mfma(const unsigned short* __restrict__ A,
                                                   const unsigned short* __restrict__ W,
                                                   const float* __restrict__ bias,
                                                   void* __restrict__ Cv,
                                                   int M, int N, int K){
  __shared__ unsigned short sA[128*32];
  __shared__ unsigned short sB[128*32];
  const int tid  = threadIdx.x;
  const int wave = tid >> 6, lane = tid & 63;
  const int lm = lane & 15, quad = lane >> 4;
  const int wm = wave & 1, wn = wave >> 1;
  const int m0 = blockIdx.y * 128, n0 = blockIdx.x * 128;

  const int r0 = tid >> 2,  c0 = (tid & 3) << 3;
  const int f1 = tid + 256;
  const int r1 = f1 >> 2,   c1 = (f1 & 3) << 3;

  f32x4 acc[4][4] = {};

  for (int kt = 0; kt < K; kt += 32){
    GLL16(&A[(size_t)(m0 + r0)*K + kt + c0], &sA[(size_t)tid*8]);
    GLL16(&A[(size_t)(m0 + r1)*K + kt + c1], &sA[(size_t)f1*8]);
    GLL16(&W[(size_t)(n0 + r0)*K + kt + c0], &sB[(size_t)tid*8]);
    GLL16(&W[(size_t)(n0 + r1)*K + kt + c1], &sB[(size_t)f1*8]);
    __syncthreads();
    bf16x8 af[4], bf[4];
    #pragma unroll
    for (int i=0;i<4;++i) af[i] = *(const bf16x8*)&sA[(wm*64 + i*16 + lm)*32 + quad*8];
    #pragma unroll
    for (int j=0;j<4;++j) bf[j] = *(const bf16x8*)&sB[(wn*64 + j*16 + lm)*32 + quad*8];
    #pragma unroll
    for (int i=0;i<4;++i)
      #pragma unroll
      for (int j=0;j<4;++j)
        acc[i][j] = __builtin_amdgcn_mfma_f32_16x16x32_bf16(af[i], bf[j], acc[i][j], 0, 0, 0);
    __syncthreads();
  }

  #pragma unroll
  for (int i=0;i<4;++i){
    #pragma unroll
    for (int r=0;r<4;++r){
      size_t m = (size_t)(m0 + wm*64 + i*16 + quad*4 + r);
      #pragma unroll
      for (int j=0;j<4;++j){
        int n = n0 + wn*64 + j*16 + lm;
        float v = acc[i][j][r];
        if (bias) v += bias[n];
        if (ACT==1) v = silu_f(v);
        if (CBF) ((unsigned short*)Cv)[m*(size_t)N + n] = f2b(v);
        else     ((float*)Cv)[m*(size_t)N + n] = v;
      }
    }
  }
}

// ---------------- prep: gates -> qe_f/ke_f in-place (SIGMA-permuted cols), exp(delta) fp16
// (sigma-permuted), eb tables (natural d). Thread owns sigma col pair (j, j+1), i.e. natural
// cols d1 = (sl&7)*16 + (sl>>3) and d2 = d1+16. In-place permutation is race-free: each block
// owns entire token rows; one barrier between the reads and the permuted writes of each token.
__global__ __launch_bounds__(256) void k_prep(unsigned short* __restrict__ qkv,
                                              const unsigned short* __restrict__ z,
                                              unsigned short* __restrict__ dbuf,
                                              unsigned short* __restrict__ ebF,
                                              unsigned short* __restrict__ ebB){
  const int blk = blockIdx.x;
  const int bb = blk / NC2, cB = blk % NC2;
  const int j  = threadIdx.x << 1;                // sigma col pair (even), 0..510
  const int cb = j & 0x180;                       // head base = hh*128
  const int sl = j & 127;
  const int d1 = ((sl & 7) << 4) | (sl >> 3);     // natural col for sigma col sl
  const int d2 = d1 + 16;                         // natural col for sigma col sl+1
  const size_t base = (size_t)bb*SEQN + cB*CH2;
  const float sc = 0.08838834764831845f;          // 128^-0.5
  float bf0[CH2], bf1[CH2];
  float r0 = 0.f, r1 = 0.f;
  #pragma unroll
  for (int t=0;t<CH2;++t){
    size_t tok = base + t;
    float z0 = b2f(z[tok*1024 + cb + d1]);
    float z1 = b2f(z[tok*1024 + cb + d2]);
    r0 += lsig16(z0);
    r1 += lsig16(z1);
    bf0[t] = r0; bf1[t] = r1;
    float qv1 = b2f(qkv[tok*2048 + cb + d1]);
    float qv2 = b2f(qkv[tok*2048 + cb + d2]);
    float kv1 = b2f(qkv[tok*2048 + 512 + cb + d1]);
    float kv2 = b2f(qkv[tok*2048 + 512 + cb + d2]);
    float e0 = __expf(r0),  e1 = __expf(r1);
    float n0 = __expf(-r0), n1 = __expf(-r1);
    unsigned qo = (unsigned)f2b(qv1*e0*sc) | ((unsigned)f2b(qv2*e1*sc) << 16);
    unsigned ko = (unsigned)f2b(kv1*n0)    | ((unsigned)f2b(kv2*n1) << 16);
    __syncthreads();   // all reads of token t done before any permuted write of token t
    *(unsigned*)&qkv[tok*2048 + j] = qo;
    *(unsigned*)&qkv[tok*2048 + 512 + j] = ko;
  }
  const int hh = j >> 7;
  {
    int ef = ((bb*NHEADS + hh)*NC2 + cB)*HQK;
    ebF[ef + d1] = f2h(__expf(bf0[CH2-1]));
    ebF[ef + d2] = f2h(__expf(bf1[CH2-1]));
  }
  r0 = 0.f; r1 = 0.f;
  #pragma unroll
  for (int t=CH2-1;t>=0;--t){
    size_t tok = base + t;
    float z0 = b2f(z[tok*1024 + 512 + cb + d1]);
    float z1 = b2f(z[tok*1024 + 512 + cb + d2]);
    r0 += lsig16(z0);
    r1 += lsig16(z1);
    float dd0 = r0 - bf0[t], dd1 = r1 - bf1[t];
    *(unsigned*)&dbuf[tok*512 + j] = (unsigned)f2h(__expf(dd0))
                                   | ((unsigned)f2h(__expf(dd1)) << 16);
  }
  {
    int eb = ((bb*NHEADS + hh)*NC2 + (NC2-1-cB))*HQK;
    ebB[eb + d1] = f2h(__expf(r0));
    ebB[eb + d2] = f2h(__expf(r1));
  }
}

// sigma-load -> sKeT[d][t] mapping: thread loads 16B pairs at sigma offset o8*16 (+8).
// kb[u]   (u=0..7, first 16B)  holds natural d = u*16 + 2*o8
// kb[u+8] (second 16B)         holds natural d = u*16 + 2*o8 + 1
#define SKET_STORE(sKeT_, kb_, o8_, ts_) \
  _Pragma("unroll") \
  for (int u=0;u<8;++u){ \
    (sKeT_)[(u*16 + 2*(o8_)    )*40 + (ts_)] = (kb_)[u]; \
    (sKeT_)[(u*16 + 2*(o8_) + 1)*40 + (ts_)] = (kb_)[u+8]; \
  }

// ---------------- GLA state-only pass: DeltaS over sub-segments of the first 66 chunks --------
// grid = 1024: bx = seg*256 + combo; seg 0..3 covers chunks [0,17),[17,33),[33,50),[50,66).
__global__ __launch_bounds__(256) void k_gla_state(const unsigned short* __restrict__ qkvb,
                                                   const unsigned short* __restrict__ dbuf,
                                                   const unsigned short* __restrict__ ebFt,
                                                   const unsigned short* __restrict__ ebBt,
                                                   float* __restrict__ dSseg){
  __shared__ __align__(16) unsigned short sKeT[128*40];  // [d][t] stride 40
  __shared__ __align__(16) unsigned short sVT[64*40];    // [v][t]
  __shared__ float sEb[128];

  const int tid = threadIdx.x;
  const int bx = blockIdx.x;
  const int combo = bx & 255, seg = bx >> 8;
  const int vq = combo & 3, dir = (combo>>2)&1, hh = (combo>>3)&3, bb = (combo>>5)&7;

  const int w = tid >> 6, lane = tid & 63;
  const int quad = lane >> 4, lm = lane & 15;
  const int ts = tid >> 3, o8 = tid & 7, d16 = o8 << 4;
  const int tl = tid & 31, vg = tid >> 5;

  const int kcol = 512 + hh*HQK, vcol = 1024 + hh*HV + vq*64;
  const int dcol = hh*HQK;
  const unsigned short* ebT = dir ? ebBt : ebFt;
  const int ebBase = (bb*NHEADS + hh)*NC2*HQK;
  const int c0 = (seg==0)?0:(seg==1)?17:(seg==2)?33:50;
  const int c1 = (seg==0)?17:(seg==1)?33:(seg==2)?50:66;

  f32x4 Sreg[8];
  #pragma unroll
  for (int i=0;i<8;++i){
    #pragma unroll
    for (int r=0;r<4;++r) Sreg[i][r] = 0.f;
  }

  for (int c = c0; c < c1; ++c){
    {
      int p = c*CH2 + ts;
      int n = dir ? (SEQN-1-p) : p;
      size_t tok = (size_t)bb*SEQN + n;
      uint4 k0 = *(const uint4*)&qkvb[tok*2048 + kcol + d16];
      uint4 k1 = *(const uint4*)&qkvb[tok*2048 + kcol + d16 + 8];
      unsigned short kb[16];
      up8(k0, kb); up8(k1, kb+8);
      if (dir){
        uint4 dd0 = *(const uint4*)&dbuf[tok*512 + dcol + d16];
        uint4 dd1 = *(const uint4*)&dbuf[tok*512 + dcol + d16 + 8];
        unsigned short eh[16];
        up8(dd0, eh); up8(dd1, eh+8);
        #pragma unroll
        for (int u=0;u<16;++u)
          kb[u] = f2b(b2f(kb[u]) * __builtin_amdgcn_rcpf(h2f(eh[u])));
      }
      SKET_STORE(sKeT, kb, o8, ts);
    }
    {
      int p = c*CH2 + tl;
      int n = dir ? (SEQN-1-p) : p;
      size_t tok = (size_t)bb*SEQN + n;
      uint4 uv = *(const uint4*)&qkvb[tok*2048 + vcol + vg*8];
      unsigned short su[8];
      up8(uv, su);
      #pragma unroll
      for (int u=0;u<8;++u) sVT[(vg*8+u)*40 + tl] = su[u];
    }
    if (tid < 128) sEb[tid] = h2f(ebT[ebBase + c*HQK + tid]);
    __syncthreads();
    bf16x8 vta = *(const bf16x8*)&sVT[(w*16+lm)*40 + quad*8];
    #pragma unroll
    for (int dt=0; dt<8; ++dt){
      bf16x8 kt = *(const bf16x8*)&sKeT[(dt*16+lm)*40 + quad*8];
      Sreg[dt] = __builtin_amdgcn_mfma_f32_16x16x32_bf16(vta, kt, Sreg[dt], 0, 0, 0);
      float eb = sEb[dt*16 + lm];
      #pragma unroll
      for (int r=0;r<4;++r) Sreg[dt][r] *= eb;
    }
    __syncthreads();
  }

  const size_t sbase = (size_t)bx * 8192;
  #pragma unroll
  for (int dt=0; dt<8; ++dt){
    #pragma unroll
    for (int r=0;r<4;++r)
      dSseg[sbase + (size_t)(w*16 + quad*4 + r)*128 + dt*16 + lm] = Sreg[dt][r];
  }
}

// ---------------- combine sub-segments into S33 and S66 ----------------
// grid = 256 (combo), 256 threads.
// S33 = DB*dA + dB ; S66 = DD*(DC*S33 + dC) + dD
__global__ __launch_bounds__(256) void k_gla_comb(const float* __restrict__ dSseg,
                                                  float* __restrict__ dSf,
                                                  const unsigned short* __restrict__ ebFt,
                                                  const unsigned short* __restrict__ ebBt){
  const int combo = blockIdx.x;
  const int dir = (combo>>2)&1, hh = (combo>>3)&3, bb = (combo>>5)&7;
  const unsigned short* ebT = dir ? ebBt : ebFt;
  const int ebBase = (bb*NHEADS + hh)*NC2*HQK;
  const int t = threadIdx.x;
  const int d0 = (t << 2) & 127;
  float DB[4]={1.f,1.f,1.f,1.f}, DC[4]={1.f,1.f,1.f,1.f}, DD[4]={1.f,1.f,1.f,1.f};
  for (int c=17; c<33; ++c){
    ushort4 ev = *(const ushort4*)&ebT[ebBase + c*HQK + d0];
    DB[0]*=h2f(ev.x); DB[1]*=h2f(ev.y); DB[2]*=h2f(ev.z); DB[3]*=h2f(ev.w);
  }
  for (int c=33; c<50; ++c){
    ushort4 ev = *(const ushort4*)&ebT[ebBase + c*HQK + d0];
    DC[0]*=h2f(ev.x); DC[1]*=h2f(ev.y); DC[2]*=h2f(ev.z); DC[3]*=h2f(ev.w);
  }
  for (int c=50; c<66; ++c){
    ushort4 ev = *(const ushort4*)&ebT[ebBase + c*HQK + d0];
    DD[0]*=h2f(ev.x); DD[1]*=h2f(ev.y); DD[2]*=h2f(ev.z); DD[3]*=h2f(ev.w);
  }
  const size_t bA = (size_t)combo*8192;
  const size_t SEG = (size_t)256*8192;
  #pragma unroll
  for (int r=0;r<8;++r){
    int idx = r*1024 + (t<<2);
    float4 a  = *(const float4*)&dSseg[bA + idx];
    float4 b4 = *(const float4*)&dSseg[bA + SEG + idx];
    float4 c4 = *(const float4*)&dSseg[bA + 2*SEG + idx];
    float4 d4 = *(const float4*)&dSseg[bA + 3*SEG + idx];
    float4 s33, s66;
    s33.x = DB[0]*a.x + b4.x; s33.y = DB[1]*a.y + b4.y;
    s33.z = DB[2]*a.z + b4.z; s33.w = DB[3]*a.w + b4.w;
    s66.x = DD[0]*(DC[0]*s33.x + c4.x) + d4.x;
    s66.y = DD[1]*(DC[1]*s33.y + c4.y) + d4.y;
    s66.z = DD[2]*(DC[2]*s33.z + c4.z) + d4.z;
    s66.w = DD[3]*(DC[3]*s33.w + c4.w) + d4.w;
    *(float4*)&dSf[bA + idx] = s33;
    *(float4*)&dSf[SEG + bA + idx] = s66;
  }
}

// ---------------- GLA chunked scan, third-of-sequence per block, CHUNK=32 ----------------
// grid = 768: bx = seg*256 + combo; seg 0: [0,33) from 0; seg 1: [33,66) from S33; seg 2: [66,98) from S66.
// sigma-permuted q/k/dbuf; sST in sigma column order (write b128); T14 prefetch of next chunk.
__global__ __launch_bounds__(256,3) void k_gla3(const unsigned short* __restrict__ qkvb,
                                                const unsigned short* __restrict__ dbuf,
                                                const unsigned short* __restrict__ ebFt,
                                                const unsigned short* __restrict__ ebBt,
                                                unsigned short* __restrict__ og,
                                                const float* __restrict__ dSf){
  __shared__ __align__(16) unsigned short sQe[32*136];   // [t][sigma-d] stride 136
  __shared__ __align__(16) unsigned short sKe[32*136];   // [t][sigma-d]
  __shared__ __align__(16) unsigned short sKeT[128*40];  // [d][t] stride 40 (natural d)
  __shared__ __align__(16) unsigned short sVT[64*40];    // [v][t]
  __shared__ __align__(16) unsigned short sST[64*136];   // [v][sigma-d] (bf16 mirror of S)
  __shared__ __align__(16) unsigned short sP[32*40];     // [t][s]
  __shared__ float sEb[128];

  const int tid = threadIdx.x;
  const int bx = blockIdx.x;
  const int combo = bx & 255, seg = bx >> 8;
  const int vq = combo & 3, dir = (combo>>2)&1, hh = (combo>>3)&3, bb = (combo>>5)&7;

  const int w = tid >> 6, lane = tid & 63;
  const int quad = lane >> 4, lm = lane & 15;
  const int mt = w >> 1, nt = w & 1;
  const int ts = tid >> 3, o8 = tid & 7, d16 = o8 << 4;  // qe/ke stage mapping
  const int tl = tid & 31, vg = tid >> 5;                // v stage mapping

  const int qcol = hh*HQK, kcol = 512 + hh*HQK, vcol = 1024 + hh*HV + vq*64;
  const int dcol = hh*HQK;
  const unsigned short* ebT = dir ? ebBt : ebFt;
  const int ebBase = (bb*NHEADS + hh)*NC2*HQK;
  const size_t ogBase = ((size_t)((dir*BBATCH + bb)*NHEADS + hh)) * SEQN * HV;

  f32x4 Sreg[8];
  #pragma unroll
  for (int i=0;i<8;++i){
    #pragma unroll
    for (int r=0;r<4;++r) Sreg[i][r] = 0.f;
  }
  if (seg){
    // load S_init (fp32, natural d) and mirror to bf16 sST at sigma cols
    const size_t sbase = ((size_t)(seg-1)*256 + combo) * 8192;
    #pragma unroll
    for (int dt=0; dt<8; ++dt){
      #pragma unroll
      for (int r=0;r<4;++r){
        float sv = dSf[sbase + (size_t)(w*16 + quad*4 + r)*128 + dt*16 + lm];
        Sreg[dt][r] = sv;
        sST[(w*16 + quad*4 + r)*136 + lm*8 + dt] = f2b(sv);  // sigma(dt*16+lm) = lm*8+dt
      }
    }
  } else {
    for (int i = tid; i < 64*136; i += 256) sST[i] = 0;
  }
  __syncthreads();

  const int cBeg = seg * 33;
  const int cEnd = (seg == 2) ? NC2 : (cBeg + 33);

  uint4 pq0, pq1, pk0, pk1, pd0, pd1, puv;
#define PREFETCH(c_) { \
    int p_ = (c_)*CH2 + ts; \
    int n_ = dir ? (SEQN-1-p_) : p_; \
    size_t tok_ = (size_t)bb*SEQN + n_; \
    pq0 = *(const uint4*)&qkvb[tok_*2048 + qcol + d16]; \
    pq1 = *(const uint4*)&qkvb[tok_*2048 + qcol + d16 + 8]; \
    pk0 = *(const uint4*)&qkvb[tok_*2048 + kcol + d16]; \
    pk1 = *(const uint4*)&qkvb[tok_*2048 + kcol + d16 + 8]; \
    if (dir){ \
      pd0 = *(const uint4*)&dbuf[tok_*512 + dcol + d16]; \
      pd1 = *(const uint4*)&dbuf[tok_*512 + dcol + d16 + 8]; \
    } \
    int pv_ = (c_)*CH2 + tl; \
    int nv_ = dir ? (SEQN-1-pv_) : pv_; \
    puv = *(const uint4*)&qkvb[((size_t)bb*SEQN + nv_)*2048 + vcol + vg*8]; \
  }

  PREFETCH(cBeg);

  for (int c = cBeg; c < cEnd; ++c){
    // ---- stage qe/ke (+backward gate fixup), v (transposed), eb — from prefetch regs ----
    {
      uint4 q0 = pq0, q1 = pq1, k0 = pk0, k1 = pk1;
      unsigned short kb[16];
      up8(k0, kb); up8(k1, kb+8);
      if (dir){
        unsigned short eh[16], qb[16];
        up8(pd0, eh); up8(pd1, eh+8);
        up8(q0, qb);  up8(q1, qb+8);
        #pragma unroll
        for (int u=0;u<16;++u){
          float e  = h2f(eh[u]);
          float ei = __builtin_amdgcn_rcpf(e);
          qb[u] = f2b(b2f(qb[u]) * e);
          kb[u] = f2b(b2f(kb[u]) * ei);
        }
        q0 = pk8(qb); q1 = pk8(qb+8);
        k0 = pk8(kb); k1 = pk8(kb+8);
      }
      *(uint4*)&sQe[ts*136 + d16]     = q0;
      *(uint4*)&sQe[ts*136 + d16 + 8] = q1;
      *(uint4*)&sKe[ts*136 + d16]     = k0;
      *(uint4*)&sKe[ts*136 + d16 + 8] = k1;
      SKET_STORE(sKeT, kb, o8, ts);
      unsigned short su[8];
      up8(puv, su);
      #pragma unroll
      for (int u=0;u<8;++u) sVT[(vg*8+u)*40 + tl] = su[u];
    }
    if (tid < 128) sEb[tid] = h2f(ebT[ebBase + c*HQK + tid]);
    __syncthreads();
    // ---- issue next chunk's global loads (latency hidden under phase1+phase2) ----
    {
      int cn = c+1 < cEnd ? c+1 : cEnd-1;
      PREFETCH(cn);
    }
    // ---- phase1: A = Qe.Ke^T ; oT += ST.Qe^T ; mask -> sP ----
    bf16x8 qf[2][4];
    #pragma unroll
    for (int tt=0; tt<2; ++tt){
      #pragma unroll
      for (int ks=0; ks<4; ++ks)
        qf[tt][ks] = *(const bf16x8*)&sQe[(tt*16+lm)*136 + ks*32 + quad*8];
    }
    f32x4 a1;
    #pragma unroll
    for (int r=0;r<4;++r) a1[r] = 0.f;
    #pragma unroll
    for (int ks=0; ks<4; ++ks){
      bf16x8 kfr = *(const bf16x8*)&sKe[(nt*16+lm)*136 + ks*32 + quad*8];
      a1 = __builtin_amdgcn_mfma_f32_16x16x32_bf16(qf[mt][ks], kfr, a1, 0, 0, 0);
    }
    f32x4 ot[2];
    #pragma unroll
    for (int tt=0; tt<2; ++tt){
      #pragma unroll
      for (int r=0;r<4;++r) ot[tt][r] = 0.f;
    }
    #pragma unroll
    for (int ks=0; ks<4; ++ks){
      bf16x8 stf = *(const bf16x8*)&sST[(w*16+lm)*136 + ks*32 + quad*8];
      #pragma unroll
      for (int tt=0; tt<2; ++tt)
        ot[tt] = __builtin_amdgcn_mfma_f32_16x16x32_bf16(stf, qf[tt][ks], ot[tt], 0, 0, 0);
    }
    #pragma unroll
    for (int r=0;r<4;++r){
      int t = mt*16 + quad*4 + r, s = nt*16 + lm;
      sP[t*40 + s] = f2b((s <= t) ? a1[r] : 0.f);
    }
    __syncthreads();
    // ---- phase2: S' = eb*(S + VT.KeT^T) ; oT += VT.P^T ; direct o store ----
    bf16x8 vta = *(const bf16x8*)&sVT[(w*16+lm)*40 + quad*8];
    #pragma unroll
    for (int dt=0; dt<8; ++dt){
      bf16x8 kt = *(const bf16x8*)&sKeT[(dt*16+lm)*40 + quad*8];
      Sreg[dt] = __builtin_amdgcn_mfma_f32_16x16x32_bf16(vta, kt, Sreg[dt], 0, 0, 0);
      float eb = sEb[dt*16 + lm];
      #pragma unroll
      for (int r=0;r<4;++r) Sreg[dt][r] *= eb;
    }
    // sST mirror: sigma cols lm*8+dt contiguous over dt -> 4 x b128 writes
    #pragma unroll
    for (int r=0;r<4;++r){
      uint4 pkv;
      pkv.x = (unsigned)f2b(Sreg[0][r]) | ((unsigned)f2b(Sreg[1][r]) << 16);
      pkv.y = (unsigned)f2b(Sreg[2][r]) | ((unsigned)f2b(Sreg[3][r]) << 16);
      pkv.z = (unsigned)f2b(Sreg[4][r]) | ((unsigned)f2b(Sreg[5][r]) << 16);
      pkv.w = (unsigned)f2b(Sreg[6][r]) | ((unsigned)f2b(Sreg[7][r]) << 16);
      *(uint4*)&sST[(w*16 + quad*4 + r)*136 + lm*8] = pkv;
    }
    #pragma unroll
    for (int tt=0; tt<2; ++tt){
      bf16x8 pf = *(const bf16x8*)&sP[(tt*16+lm)*40 + quad*8];
      ot[tt] = __builtin_amdgcn_mfma_f32_16x16x32_bf16(vta, pf, ot[tt], 0, 0, 0);
      // direct store: o[t = tt*16+lm][v = w*16 + quad*4 + r], r=0..3 packed as 8B
      int p = c*CH2 + tt*16 + lm;
      int n = dir ? (SEQN-1-p) : p;
      ushort4 o4;
      o4.x = f2b(ot[tt][0]); o4.y = f2b(ot[tt][1]);
      o4.z = f2b(ot[tt][2]); o4.w = f2b(ot[tt][3]);
      *(ushort4*)&og[ogBase + (size_t)n*HV + vq*64 + w*16 + quad*4] = o4;
    }
    __syncthreads();
  } // chunks
#undef PREFETCH
}

// ---------------- rmsnorm(f)+rmsnorm(b), gate with silu(g) ----------------
__global__ __launch_bounds__(256) void k_gate(const unsigned short* __restrict__ og,
                                              const unsigned short* __restrict__ g,
                                              const float* __restrict__ gnw,
                                              const float* __restrict__ lnw,
                                              unsigned short* __restrict__ y){
  int tok = blockIdx.x;
  int bb = tok / SEQN, n = tok % SEQN;
  int hh = threadIdx.x >> 6, l = threadIdx.x & 63;
  int j4 = l << 2;
  size_t basef = ((size_t)((0*BBATCH+bb)*NHEADS+hh))*SEQN*HV + (size_t)n*HV + j4;
  size_t baseb = ((size_t)((1*BBATCH+bb)*NHEADS+hh))*SEQN*HV + (size_t)n*HV + j4;
  ushort4 ofu = *(const ushort4*)&og[basef];
  ushort4 obu = *(const ushort4*)&og[baseb];
  float of0=b2f(ofu.x), of1=b2f(ofu.y), of2=b2f(ofu.z), of3=b2f(ofu.w);
  float ob0=b2f(obu.x), ob1=b2f(obu.y), ob2=b2f(obu.z), ob3=b2f(obu.w);
  float ssf = of0*of0 + of1*of1 + of2*of2 + of3*of3;
  float ssb = ob0*ob0 + ob1*ob1 + ob2*ob2 + ob3*ob3;
  #pragma unroll
  for (int m=32;m>=1;m>>=1){ ssf += __shfl_xor(ssf,m,64); ssb += __shfl_xor(ssb,m,64); }
  float rf = rsqrtf(ssf*(1.f/HV) + 1e-5f);
  float rb = rsqrtf(ssb*(1.f/HV) + 1e-5f);
  float4 gn = *(const float4*)&gnw[j4];
  float4 ln = *(const float4*)&lnw[j4];
  ushort4 gvu = *(const ushort4*)&g[(size_t)tok*1024 + hh*HV + j4];  // silu already applied
  float g0=b2f(gvu.x), g1=b2f(gvu.y), g2=b2f(gvu.z), g3=b2f(gvu.w);
  ushort4 out;
  out.x = f2b(g0*(of0*rf*gn.x + ob0*rb*ln.x));
  out.y = f2b(g1*(of1*rf*gn.y + ob1*rb*ln.y));
  out.z = f2b(g2*(of2*rf*gn.z + ob2*rb*ln.z));
  out.w = f2b(g3*(of3*rf*gn.w + ob3*rb*ln.w));
  *(ushort4*)&y[(size_t)tok*1024 + hh*HV + j4] = out;
}

extern "C" void kernel_launch(void* const* d_in, const int* in_sizes, int n_in,
                              void* d_out, int out_size, void* d_ws, size_t ws_size,
                              hipStream_t stream){
  (void)in_sizes; (void)n_in; (void)out_size;
  const float* x    = (const float*)d_in[0];
  const float* cw   = (const float*)d_in[1];
  const float* qkvw = (const float*)d_in[2];
  const float* gkw1 = (const float*)d_in[3];
  const float* gkw2 = (const float*)d_in[4];
  const float* gkb2 = (const float*)d_in[5];
  const float* gw   = (const float*)d_in[6];
  const float* gb   = (const float*)d_in[7];
  const float* gnw  = (const float*)d_in[8];
  const float* lnw  = (const float*)d_in[9];
  const float* ow   = (const float*)d_in[10];

  // Workspace layout (bytes), total 232,816,640 (proven budget):
  //   qkv  bf16 [25088,2048]  @ 0           (103 MB) — prep overwrites q/k (sigma cols); reused
  //        as y (first 51.4MB) + g (second 51.4MB) after k_gla3 when qkv is dead
  //   og   bf16 [2,8,4,3136,256] @ 102760448 (103 MB)
  //        pre-gla3 overlays: dSseg fp32 [4,256,64,128] @ +0 (33.6 MB), zbuf @ +25690112
  //        (51.4 MB, dead after prep), wqb @ +77070336 (2 MB), wc @ +80216064 (1 MB);
  //        wob @ +0 after k_gate.
  //   dbuf fp16 exp(delta) sigma cols [25088,512] @ 205520896 (25.7 MB)
  //   ebF  fp16 [8,4,98,128]  @ 231211008   (0.8 MB)
  //   ebB  fp16 [8,4,98,128]  @ 232013824   (0.8 MB)
  // d_out (51.4 MB) scratch until final GEMM:
  //   xs  bf16 [25088,512] @ 0 (25.7 MB) — survives until g-GEMM (after gla)
  //   dSf fp32 [2,256,64,128] @ 25690112 (16.8 MB) — S33/S66 for segs 1,2
  //   wgb bf16 [1024,512] @ 42467328 (1 MB)
  if (ws_size < 232816640u) return;
  char* wsb = (char*)d_ws;
  char* dob = (char*)d_out;
  unsigned short* qkv  = (unsigned short*)(wsb + 0);
  unsigned short* g    = (unsigned short*)(wsb + 51380224);
  unsigned short* og   = (unsigned short*)(wsb + 102760448);
  float*          dSseg= (float*)(wsb + 102760448);
  unsigned short* zbuf = (unsigned short*)(wsb + 102760448 + 25690112);
  unsigned short* wqb  = (unsigned short*)(wsb + 102760448 + 77070336);
  unsigned short* wc   = (unsigned short*)(wsb + 102760448 + 80216064);
  unsigned short* dbuf = (unsigned short*)(wsb + 205520896);
  unsigned short* ebF  = (unsigned short*)(wsb + 231211008);
  unsigned short* ebB  = (unsigned short*)(wsb + 232013824);
  unsigned short* xs   = (unsigned short*)(dob + 0);
  float*          dSf  = (float*)(dob + 25690112);
  unsigned short* wgb  = (unsigned short*)(dob + 42467328);
  unsigned short* wob  = og;                         // after k_gate, og dead
  unsigned short* y    = qkv;                        // qkv dead after k_gla3
  float*          outp = (float*)d_out;

  k_conv_silu<<<NTOK*128/256, 256, 0, stream>>>(x, cw, xs);
  k_w2b<<<1024, 256, 0, stream>>>(qkvw, wqb, 2048*512);
  k_w2b<<<512,  256, 0, stream>>>(gw,   wgb, 1024*512);
  k_wc<<<2048, 256, 0, stream>>>(gkw1, gkw2, wc);
  k_gemm_mfma<0,1><<<dim3(16,196), 256, 0, stream>>>(xs, wqb, nullptr, qkv,  NTOK, 2048, 512);
  k_gemm_mfma<0,1><<<dim3(8,196),  256, 0, stream>>>(xs, wc,  gkb2,    zbuf, NTOK, 1024, 512);
  k_prep<<<BBATCH*NC2, 256, 0, stream>>>(qkv, zbuf, dbuf, ebF, ebB);
  k_gla_state<<<1024, 256, 0, stream>>>(qkv, dbuf, ebF, ebB, dSseg);
  k_gla_comb<<<256, 256, 0, stream>>>(dSseg, dSf, ebF, ebB);
  k_gla3<<<768, 256, 0, stream>>>(qkv, dbuf, ebF, ebB, og, dSf);
  k_gemm_mfma<1,1><<<dim3(8,196),  256, 0, stream>>>(xs, wgb, gb, g, NTOK, 1024, 512);
  k_gate<<<NTOK, 256, 0, stream>>>(og, g, gnw, lnw, y);
  k_w2b<<<512, 256, 0, stream>>>(ow, wob, 512*1024);
  k_gemm_mfma<0,0><<<dim3(4,196), 256, 0, stream>>>(y, wob, nullptr, outp, NTOK, 512, 1024);
}

// Round 7
// 1134.778 us; speedup vs baseline: 1.3507x; 1.3507x over previous
//
#include <hip/hip_runtime.h>
#include <hip/hip_bf16.h>
#include <math.h>

#define NHEADS 4
#define DMODEL 512
#define HQK 128
#define HV 256
#define BBATCH 8
#define SH 56
#define SWW 56
#define SEQN (SH*SWW)          // 3136
#define NTOK (BBATCH*SEQN)     // 25088
#define CH2 32
#define NC2 (SEQN/CH2)         // 98

// sigma column permutation within each 128-col head: sigma(d) = (d&15)*8 + (d>>4).
// q/k/dbuf are stored sigma-permuted by k_prep; V, eb tables, dS stay natural.

typedef __bf16 bf16x8 __attribute__((ext_vector_type(8)));
typedef float  f32x4  __attribute__((ext_vector_type(4)));

__device__ __forceinline__ float silu_f(float v){ return v / (1.f + __expf(-v)); }

__device__ __forceinline__ float b2f(unsigned short u){
  union { unsigned int i; float f; } c; c.i = ((unsigned int)u) << 16; return c.f;
}
__device__ __forceinline__ unsigned short f2b(float f){
  __bf16 h = (__bf16)f;
  unsigned short u; __builtin_memcpy(&u, &h, 2); return u;
}
__device__ __forceinline__ float h2f(unsigned short u){
  _Float16 h; __builtin_memcpy(&h, &u, 2); return (float)h;
}
__device__ __forceinline__ unsigned short f2h(float f){
  _Float16 h = (_Float16)f; unsigned short u; __builtin_memcpy(&u, &h, 2); return u;
}
__device__ __forceinline__ float lsig16(float z){          // logsigmoid(z)/16
  float e = __expf(-fabsf(z));
  return (fminf(z, 0.f) - __logf(1.f + e)) * 0.0625f;
}
__device__ __forceinline__ void up8(uint4 v, unsigned short* o){
  o[0]=(unsigned short)v.x; o[1]=(unsigned short)(v.x>>16);
  o[2]=(unsigned short)v.y; o[3]=(unsigned short)(v.y>>16);
  o[4]=(unsigned short)v.z; o[5]=(unsigned short)(v.z>>16);
  o[6]=(unsigned short)v.w; o[7]=(unsigned short)(v.w>>16);
}
__device__ __forceinline__ uint4 pk8(const unsigned short* s){
  uint4 v;
  v.x = (unsigned)s[0] | ((unsigned)s[1]<<16);
  v.y = (unsigned)s[2] | ((unsigned)s[3]<<16);
  v.z = (unsigned)s[4] | ((unsigned)s[5]<<16);
  v.w = (unsigned)s[6] | ((unsigned)s[7]<<16);
  return v;
}

#define GLL16(gp, lp) __builtin_amdgcn_global_load_lds( \
    (const __attribute__((address_space(1))) unsigned int*)(gp), \
    (__attribute__((address_space(3))) unsigned int*)(lp), 16, 0, 0)

// ---------------- fp32 -> bf16 weight conversion ----------------
__global__ __launch_bounds__(256) void k_w2b(const float* __restrict__ w,
                                             unsigned short* __restrict__ o, int n){
  int i = (blockIdx.x*256 + threadIdx.x) << 2;
  if (i >= n) return;
  float4 v = *(const float4*)&w[i];
  ushort4 p;
  p.x = f2b(v.x); p.y = f2b(v.y); p.z = f2b(v.z); p.w = f2b(v.w);
  *(ushort4*)&o[i] = p;
}

// ---------------- Wc = gk_w2[1024,16] @ gk_w1[16,512] -> bf16 [1024][512] ----------------
__global__ __launch_bounds__(256) void k_wc(const float* __restrict__ w1,
                                            const float* __restrict__ w2,
                                            unsigned short* __restrict__ wc){
  int idx = blockIdx.x*256 + threadIdx.x;   // n*512 + k
  int n = idx >> 9, k = idx & 511;
  float acc = 0.f;
  #pragma unroll
  for (int r=0;r<16;++r) acc += w2[n*16+r]*w1[r*512+k];
  wc[idx] = f2b(acc);
}

// ---------------- conv 3x3 depthwise + SiLU -> xs (bf16) ----------------
__global__ __launch_bounds__(256) void k_conv_silu(const float* __restrict__ x,
                                                   const float* __restrict__ cw,
                                                   unsigned short* __restrict__ xs){
  int gid = blockIdx.x*256 + threadIdx.x;     // NTOK*128 threads
  int c4  = (gid & 127) << 2;
  int tok = gid >> 7;
  int b = tok / SEQN, sp = tok % SEQN;
  int hh = sp / SWW, ww = sp % SWW;
  float a0=0.f,a1=0.f,a2=0.f,a3=0.f;
  #pragma unroll
  for (int dh=-1; dh<=1; ++dh){
    int h2 = hh+dh; if (h2<0||h2>=SH) continue;
    #pragma unroll
    for (int dw=-1; dw<=1; ++dw){
      int w2 = ww+dw; if (w2<0||w2>=SWW) continue;
      const float4 xv = *(const float4*)&x[((size_t)(b*SEQN + h2*SWW + w2))*DMODEL + c4];
      int tap = (dh+1)*3 + (dw+1);
      a0 += xv.x * cw[(c4+0)*9 + tap];
      a1 += xv.y * cw[(c4+1)*9 + tap];
      a2 += xv.z * cw[(c4+2)*9 + tap];
      a3 += xv.w * cw[(c4+3)*9 + tap];
    }
  }
  ushort4 o;
  o.x = f2b(silu_f(a0)); o.y = f2b(silu_f(a1)); o.z = f2b(silu_f(a2)); o.w = f2b(silu_f(a3));
  *(ushort4*)&xs[(size_t)tok*DMODEL + c4] = o;
}

// ------- MFMA GEMM: C[M,N] = act(A_bf16[M,K] * W_bf16[N,K]^T + bias) -------
template<int ACT, int CBF>
__global__ __launch_bounds__(256) void k_gemm_mfma(const unsigned short* __restrict__ A,
                                                   const unsigned short* __restrict__ W,
                                                   const float* __restrict__ bias,
                                                   void* __restrict__ Cv,
                                                   int M, int N, int K){
  __shared__ unsigned short sA[128*32];
  __shared__ unsigned short sB[128*32];
  const int tid  = threadIdx.x;
  const int wave = tid >> 6, lane = tid & 63;
  const int lm = lane & 15, quad = lane >> 4;
  const int wm = wave & 1, wn = wave >> 1;
  const int m0 = blockIdx.y * 128, n0 = blockIdx.x * 128;

  const int r0 = tid >> 2,  c0 = (tid & 3) << 3;
  const int f1 = tid + 256;
  const int r1 = f1 >> 2,   c1 = (f1 & 3) << 3;

  f32x4 acc[4][4] = {};

  for (int kt = 0; kt < K; kt += 32){
    GLL16(&A[(size_t)(m0 + r0)*K + kt + c0], &sA[(size_t)tid*8]);
    GLL16(&A[(size_t)(m0 + r1)*K + kt + c1], &sA[(size_t)f1*8]);
    GLL16(&W[(size_t)(n0 + r0)*K + kt + c0], &sB[(size_t)tid*8]);
    GLL16(&W[(size_t)(n0 + r1)*K + kt + c1], &sB[(size_t)f1*8]);
    __syncthreads();
    bf16x8 af[4], bf[4];
    #pragma unroll
    for (int i=0;i<4;++i) af[i] = *(const bf16x8*)&sA[(wm*64 + i*16 + lm)*32 + quad*8];
    #pragma unroll
    for (int j=0;j<4;++j) bf[j] = *(const bf16x8*)&sB[(wn*64 + j*16 + lm)*32 + quad*8];
    #pragma unroll
    for (int i=0;i<4;++i)
      #pragma unroll
      for (int j=0;j<4;++j)
        acc[i][j] = __builtin_amdgcn_mfma_f32_16x16x32_bf16(af[i], bf[j], acc[i][j], 0, 0, 0);
    __syncthreads();
  }

  #pragma unroll
  for (int i=0;i<4;++i){
    #pragma unroll
    for (int r=0;r<4;++r){
      size_t m = (size_t)(m0 + wm*64 + i*16 + quad*4 + r);
      #pragma unroll
      for (int j=0;j<4;++j){
        int n = n0 + wn*64 + j*16 + lm;
        float v = acc[i][j][r];
        if (bias) v += bias[n];
        if (ACT==1) v = silu_f(v);
        if (CBF) ((unsigned short*)Cv)[m*(size_t)N + n] = f2b(v);
        else     ((float*)Cv)[m*(size_t)N + n] = v;
      }
    }
  }
}

// ---------------- prep: gates -> qe_f/ke_f in-place (SIGMA-permuted cols), exp(delta) fp16
// (sigma-permuted), eb tables (natural d). Verified R6 (absmax bit-identical).
__global__ __launch_bounds__(256) void k_prep(unsigned short* __restrict__ qkv,
                                              const unsigned short* __restrict__ z,
                                              unsigned short* __restrict__ dbuf,
                                              unsigned short* __restrict__ ebF,
                                              unsigned short* __restrict__ ebB){
  const int blk = blockIdx.x;
  const int bb = blk / NC2, cB = blk % NC2;
  const int j  = threadIdx.x << 1;                // sigma col pair (even), 0..510
  const int cb = j & 0x180;                       // head base = hh*128
  const int sl = j & 127;
  const int d1 = ((sl & 7) << 4) | (sl >> 3);     // natural col for sigma col sl
  const int d2 = d1 + 16;                         // natural col for sigma col sl+1
  const size_t base = (size_t)bb*SEQN + cB*CH2;
  const float sc = 0.08838834764831845f;          // 128^-0.5
  float bf0[CH2], bf1[CH2];
  float r0 = 0.f, r1 = 0.f;
  #pragma unroll
  for (int t=0;t<CH2;++t){
    size_t tok = base + t;
    float z0 = b2f(z[tok*1024 + cb + d1]);
    float z1 = b2f(z[tok*1024 + cb + d2]);
    r0 += lsig16(z0);
    r1 += lsig16(z1);
    bf0[t] = r0; bf1[t] = r1;
    float qv1 = b2f(qkv[tok*2048 + cb + d1]);
    float qv2 = b2f(qkv[tok*2048 + cb + d2]);
    float kv1 = b2f(qkv[tok*2048 + 512 + cb + d1]);
    float kv2 = b2f(qkv[tok*2048 + 512 + cb + d2]);
    float e0 = __expf(r0),  e1 = __expf(r1);
    float n0 = __expf(-r0), n1 = __expf(-r1);
    unsigned qo = (unsigned)f2b(qv1*e0*sc) | ((unsigned)f2b(qv2*e1*sc) << 16);
    unsigned ko = (unsigned)f2b(kv1*n0)    | ((unsigned)f2b(kv2*n1) << 16);
    __syncthreads();   // all reads of token t done before any permuted write of token t
    *(unsigned*)&qkv[tok*2048 + j] = qo;
    *(unsigned*)&qkv[tok*2048 + 512 + j] = ko;
  }
  const int hh = j >> 7;
  {
    int ef = ((bb*NHEADS + hh)*NC2 + cB)*HQK;
    ebF[ef + d1] = f2h(__expf(bf0[CH2-1]));
    ebF[ef + d2] = f2h(__expf(bf1[CH2-1]));
  }
  r0 = 0.f; r1 = 0.f;
  #pragma unroll
  for (int t=CH2-1;t>=0;--t){
    size_t tok = base + t;
    float z0 = b2f(z[tok*1024 + 512 + cb + d1]);
    float z1 = b2f(z[tok*1024 + 512 + cb + d2]);
    r0 += lsig16(z0);
    r1 += lsig16(z1);
    float dd0 = r0 - bf0[t], dd1 = r1 - bf1[t];
    *(unsigned*)&dbuf[tok*512 + j] = (unsigned)f2h(__expf(dd0))
                                   | ((unsigned)f2h(__expf(dd1)) << 16);
  }
  {
    int eb = ((bb*NHEADS + hh)*NC2 + (NC2-1-cB))*HQK;
    ebB[eb + d1] = f2h(__expf(r0));
    ebB[eb + d2] = f2h(__expf(r1));
  }
}

// sigma-load -> sKeT[d][t] mapping: thread loads 16B pairs at sigma offset o8*16 (+8).
#define SKET_STORE(sKeT_, kb_, o8_, ts_) \
  _Pragma("unroll") \
  for (int u=0;u<8;++u){ \
    (sKeT_)[(u*16 + 2*(o8_)    )*40 + (ts_)] = (kb_)[u]; \
    (sKeT_)[(u*16 + 2*(o8_) + 1)*40 + (ts_)] = (kb_)[u+8]; \
  }

// ---------------- GLA state-only pass: DeltaS over sub-segments of the first 74 chunks --------
// grid = 1536: bx = seg*256 + combo; seg 0..5 covers [0,13),[13,25),[25,37),[37,50),[50,62),[62,74).
// combo = vq | dir<<2 | hh<<3 | bb<<5.
__global__ __launch_bounds__(256) void k_gla_state(const unsigned short* __restrict__ qkvb,
                                                   const unsigned short* __restrict__ dbuf,
                                                   const unsigned short* __restrict__ ebFt,
                                                   const unsigned short* __restrict__ ebBt,
                                                   float* __restrict__ dSseg){
  __shared__ __align__(16) unsigned short sKeT[128*40];  // [d][t] stride 40
  __shared__ __align__(16) unsigned short sVT[64*40];    // [v][t]
  __shared__ float sEb[128];

  const int tid = threadIdx.x;
  const int bx = blockIdx.x;
  const int combo = bx & 255, seg = bx >> 8;
  const int vq = combo & 3, dir = (combo>>2)&1, hh = (combo>>3)&3, bb = (combo>>5)&7;

  const int w = tid >> 6, lane = tid & 63;
  const int quad = lane >> 4, lm = lane & 15;
  const int ts = tid >> 3, o8 = tid & 7, d16 = o8 << 4;
  const int tl = tid & 31, vg = tid >> 5;

  const int kcol = 512 + hh*HQK, vcol = 1024 + hh*HV + vq*64;
  const int dcol = hh*HQK;
  const unsigned short* ebT = dir ? ebBt : ebFt;
  const int ebBase = (bb*NHEADS + hh)*NC2*HQK;
  const int c0 = (seg==0)?0:(seg==1)?13:(seg==2)?25:(seg==3)?37:(seg==4)?50:62;
  const int c1 = (seg==0)?13:(seg==1)?25:(seg==2)?37:(seg==3)?50:(seg==4)?62:74;

  f32x4 Sreg[8];
  #pragma unroll
  for (int i=0;i<8;++i){
    #pragma unroll
    for (int r=0;r<4;++r) Sreg[i][r] = 0.f;
  }

  for (int c = c0; c < c1; ++c){
    {
      int p = c*CH2 + ts;
      int n = dir ? (SEQN-1-p) : p;
      size_t tok = (size_t)bb*SEQN + n;
      uint4 k0 = *(const uint4*)&qkvb[tok*2048 + kcol + d16];
      uint4 k1 = *(const uint4*)&qkvb[tok*2048 + kcol + d16 + 8];
      unsigned short kb[16];
      up8(k0, kb); up8(k1, kb+8);
      if (dir){
        uint4 dd0 = *(const uint4*)&dbuf[tok*512 + dcol + d16];
        uint4 dd1 = *(const uint4*)&dbuf[tok*512 + dcol + d16 + 8];
        unsigned short eh[16];
        up8(dd0, eh); up8(dd1, eh+8);
        #pragma unroll
        for (int u=0;u<16;++u)
          kb[u] = f2b(b2f(kb[u]) * __builtin_amdgcn_rcpf(h2f(eh[u])));
      }
      SKET_STORE(sKeT, kb, o8, ts);
    }
    {
      int p = c*CH2 + tl;
      int n = dir ? (SEQN-1-p) : p;
      size_t tok = (size_t)bb*SEQN + n;
      uint4 uv = *(const uint4*)&qkvb[tok*2048 + vcol + vg*8];
      unsigned short su[8];
      up8(uv, su);
      #pragma unroll
      for (int u=0;u<8;++u) sVT[(vg*8+u)*40 + tl] = su[u];
    }
    if (tid < 128) sEb[tid] = h2f(ebT[ebBase + c*HQK + tid]);
    __syncthreads();
    bf16x8 vta = *(const bf16x8*)&sVT[(w*16+lm)*40 + quad*8];
    #pragma unroll
    for (int dt=0; dt<8; ++dt){
      bf16x8 kt = *(const bf16x8*)&sKeT[(dt*16+lm)*40 + quad*8];
      Sreg[dt] = __builtin_amdgcn_mfma_f32_16x16x32_bf16(vta, kt, Sreg[dt], 0, 0, 0);
      float eb = sEb[dt*16 + lm];
      #pragma unroll
      for (int r=0;r<4;++r) Sreg[dt][r] *= eb;
    }
    __syncthreads();
  }

  const size_t sbase = (size_t)bx * 8192;
  #pragma unroll
  for (int dt=0; dt<8; ++dt){
    #pragma unroll
    for (int r=0;r<4;++r)
      dSseg[sbase + (size_t)(w*16 + quad*4 + r)*128 + dt*16 + lm] = Sreg[dt][r];
  }
}

// ---------------- combine sub-segments into S25, S50, S74 ----------------
// grid = 256 (combo), 256 threads.
// S25 = D1*d0 + d1 ; S50 = D3*(D2*S25 + d2) + d3 ; S74 = D5*(D4*S50 + d4) + d5
__global__ __launch_bounds__(256) void k_gla_comb(const float* __restrict__ dSseg,
                                                  float* __restrict__ dSf,
                                                  const unsigned short* __restrict__ ebFt,
                                                  const unsigned short* __restrict__ ebBt){
  const int combo = blockIdx.x;
  const int dir = (combo>>2)&1, hh = (combo>>3)&3, bb = (combo>>5)&7;
  const unsigned short* ebT = dir ? ebBt : ebFt;
  const int ebBase = (bb*NHEADS + hh)*NC2*HQK;
  const int t = threadIdx.x;
  const int d0 = (t << 2) & 127;
  float D1[4]={1,1,1,1}, D2[4]={1,1,1,1}, D3[4]={1,1,1,1}, D4[4]={1,1,1,1}, D5[4]={1,1,1,1};
  for (int c=13; c<25; ++c){
    ushort4 ev = *(const ushort4*)&ebT[ebBase + c*HQK + d0];
    D1[0]*=h2f(ev.x); D1[1]*=h2f(ev.y); D1[2]*=h2f(ev.z); D1[3]*=h2f(ev.w);
  }
  for (int c=25; c<37; ++c){
    ushort4 ev = *(const ushort4*)&ebT[ebBase + c*HQK + d0];
    D2[0]*=h2f(ev.x); D2[1]*=h2f(ev.y); D2[2]*=h2f(ev.z); D2[3]*=h2f(ev.w);
  }
  for (int c=37; c<50; ++c){
    ushort4 ev = *(const ushort4*)&ebT[ebBase + c*HQK + d0];
    D3[0]*=h2f(ev.x); D3[1]*=h2f(ev.y); D3[2]*=h2f(ev.z); D3[3]*=h2f(ev.w);
  }
  for (int c=50; c<62; ++c){
    ushort4 ev = *(const ushort4*)&ebT[ebBase + c*HQK + d0];
    D4[0]*=h2f(ev.x); D4[1]*=h2f(ev.y); D4[2]*=h2f(ev.z); D4[3]*=h2f(ev.w);
  }
  for (int c=62; c<74; ++c){
    ushort4 ev = *(const ushort4*)&ebT[ebBase + c*HQK + d0];
    D5[0]*=h2f(ev.x); D5[1]*=h2f(ev.y); D5[2]*=h2f(ev.z); D5[3]*=h2f(ev.w);
  }
  const size_t bA = (size_t)combo*8192;
  const size_t SEG = (size_t)256*8192;
  #pragma unroll
  for (int r=0;r<8;++r){
    int idx = r*1024 + (t<<2);
    float4 a0 = *(const float4*)&dSseg[bA + idx];
    float4 a1 = *(const float4*)&dSseg[bA + SEG + idx];
    float4 a2 = *(const float4*)&dSseg[bA + 2*SEG + idx];
    float4 a3 = *(const float4*)&dSseg[bA + 3*SEG + idx];
    float4 a4 = *(const float4*)&dSseg[bA + 4*SEG + idx];
    float4 a5 = *(const float4*)&dSseg[bA + 5*SEG + idx];
    float4 s25, s50, s74;
    s25.x = D1[0]*a0.x + a1.x; s25.y = D1[1]*a0.y + a1.y;
    s25.z = D1[2]*a0.z + a1.z; s25.w = D1[3]*a0.w + a1.w;
    s50.x = D3[0]*(D2[0]*s25.x + a2.x) + a3.x;
    s50.y = D3[1]*(D2[1]*s25.y + a2.y) + a3.y;
    s50.z = D3[2]*(D2[2]*s25.z + a2.z) + a3.z;
    s50.w = D3[3]*(D2[3]*s25.w + a2.w) + a3.w;
    s74.x = D5[0]*(D4[0]*s50.x + a4.x) + a5.x;
    s74.y = D5[1]*(D4[1]*s50.y + a4.y) + a5.y;
    s74.z = D5[2]*(D4[2]*s50.z + a4.z) + a5.z;
    s74.w = D5[3]*(D4[3]*s50.w + a4.w) + a5.w;
    *(float4*)&dSf[bA + idx] = s25;
    *(float4*)&dSf[SEG + bA + idx] = s50;
    *(float4*)&dSf[2*SEG + bA + idx] = s74;
  }
}

// ---------------- GLA chunked scan, vq-MERGED (v-width 128), quarter-sequence per block ------
// grid = 512: bx = seg*128 + combo; combo = vp | dir<<1 | hh<<2 | bb<<4 (128 combos).
// seg 0: [0,25) from 0; seg 1: [25,50) from S25; seg 2: [50,74) from S50; seg 3: [74,98) from S74.
// LDS = 75,776 B -> 2 blocks/CU.
__global__ __launch_bounds__(256,2) void k_gla3(const unsigned short* __restrict__ qkvb,
                                                const unsigned short* __restrict__ dbuf,
                                                const unsigned short* __restrict__ ebFt,
                                                const unsigned short* __restrict__ ebBt,
                                                unsigned short* __restrict__ og,
                                                const float* __restrict__ dSf){
  __shared__ __align__(16) unsigned short sQe[32*136];    // [t][sigma-d]
  __shared__ __align__(16) unsigned short sKe[32*136];    // [t][sigma-d]
  __shared__ __align__(16) unsigned short sKeT[128*40];   // [d][t] natural d
  __shared__ __align__(16) unsigned short sVT[128*40];    // [v128][t]
  __shared__ __align__(16) unsigned short sST[128*136];   // [v128][sigma-d]
  __shared__ __align__(16) unsigned short sP[32*40];      // [t][s]
  __shared__ float sEb[128];

  const int tid = threadIdx.x;
  const int bx = blockIdx.x;
  const int combo = bx & 127, seg = bx >> 7;
  const int vp = combo & 1, dir = (combo>>1)&1, hh = (combo>>2)&3, bb = (combo>>4)&7;

  const int w = tid >> 6, lane = tid & 63;
  const int quad = lane >> 4, lm = lane & 15;
  const int mt = w >> 1, nt = w & 1;
  const int ts = tid >> 3, o8 = tid & 7, d16 = o8 << 4;  // qe/ke stage mapping
  const int tl = tid & 31, vg = tid >> 5;                // v stage mapping

  const int qcol = hh*HQK, kcol = 512 + hh*HQK, vcol = 1024 + hh*HV + vp*128;
  const int dcol = hh*HQK;
  const unsigned short* ebT = dir ? ebBt : ebFt;
  const int ebBase = (bb*NHEADS + hh)*NC2*HQK;
  const size_t ogBase = ((size_t)((dir*BBATCH + bb)*NHEADS + hh)) * SEQN * HV;

  f32x4 Sreg[2][8];
  #pragma unroll
  for (int vh=0; vh<2; ++vh)
    #pragma unroll
    for (int i=0;i<8;++i)
      #pragma unroll
      for (int r=0;r<4;++r) Sreg[vh][i][r] = 0.f;
  if (seg){
    #pragma unroll
    for (int vh=0; vh<2; ++vh){
      const int combo_s = (vp*2+vh) | (dir<<2) | (hh<<3) | (bb<<5);
      const size_t sbase = ((size_t)(seg-1)*256 + combo_s) * 8192;
      #pragma unroll
      for (int dt=0; dt<8; ++dt){
        #pragma unroll
        for (int r=0;r<4;++r){
          float sv = dSf[sbase + (size_t)(w*16 + quad*4 + r)*128 + dt*16 + lm];
          Sreg[vh][dt][r] = sv;
          sST[(vh*64 + w*16 + quad*4 + r)*136 + lm*8 + dt] = f2b(sv);
        }
      }
    }
  } else {
    for (int i = tid; i < 128*136; i += 256) sST[i] = 0;
  }
  __syncthreads();

  const int cBeg = (seg==0)?0:(seg==1)?25:(seg==2)?50:74;
  const int cEnd = (seg==0)?25:(seg==1)?50:(seg==2)?74:98;

  for (int c = cBeg; c < cEnd; ++c){
    // ---- stage qe/ke (+backward gate fixup), v (two 64-halves), eb ----
    {
      int p = c*CH2 + ts;
      int n = dir ? (SEQN-1-p) : p;
      size_t tok = (size_t)bb*SEQN + n;
      uint4 q0 = *(const uint4*)&qkvb[tok*2048 + qcol + d16];
      uint4 q1 = *(const uint4*)&qkvb[tok*2048 + qcol + d16 + 8];
      uint4 k0 = *(const uint4*)&qkvb[tok*2048 + kcol + d16];
      uint4 k1 = *(const uint4*)&qkvb[tok*2048 + kcol + d16 + 8];
      unsigned short kb[16];
      up8(k0, kb); up8(k1, kb+8);
      if (dir){
        uint4 dd0 = *(const uint4*)&dbuf[tok*512 + dcol + d16];
        uint4 dd1 = *(const uint4*)&dbuf[tok*512 + dcol + d16 + 8];
        unsigned short eh[16], qb[16];
        up8(dd0, eh); up8(dd1, eh+8);
        up8(q0, qb);  up8(q1, qb+8);
        #pragma unroll
        for (int u=0;u<16;++u){
          float e  = h2f(eh[u]);
          float ei = __builtin_amdgcn_rcpf(e);
          qb[u] = f2b(b2f(qb[u]) * e);
          kb[u] = f2b(b2f(kb[u]) * ei);
        }
        q0 = pk8(qb); q1 = pk8(qb+8);
        k0 = pk8(kb); k1 = pk8(kb+8);
      }
      *(uint4*)&sQe[ts*136 + d16]     = q0;
      *(uint4*)&sQe[ts*136 + d16 + 8] = q1;
      *(uint4*)&sKe[ts*136 + d16]     = k0;
      *(uint4*)&sKe[ts*136 + d16 + 8] = k1;
      SKET_STORE(sKeT, kb, o8, ts);
      int pv = c*CH2 + tl;
      int nv = dir ? (SEQN-1-pv) : pv;
      size_t tokv = (size_t)bb*SEQN + nv;
      uint4 uv0 = *(const uint4*)&qkvb[tokv*2048 + vcol + vg*8];
      uint4 uv1 = *(const uint4*)&qkvb[tokv*2048 + vcol + 64 + vg*8];
      unsigned short su[8];
      up8(uv0, su);
      #pragma unroll
      for (int u=0;u<8;++u) sVT[(vg*8+u)*40 + tl] = su[u];
      up8(uv1, su);
      #pragma unroll
      for (int u=0;u<8;++u) sVT[(64+vg*8+u)*40 + tl] = su[u];
    }
    if (tid < 128) sEb[tid] = h2f(ebT[ebBase + c*HQK + tid]);
    __syncthreads();
    // ---- phase1: A = Qe.Ke^T ; oT += ST.Qe^T (both v-halves) ; mask -> sP ----
    bf16x8 qf[2][4];
    #pragma unroll
    for (int tt=0; tt<2; ++tt){
      #pragma unroll
      for (int ks=0; ks<4; ++ks)
        qf[tt][ks] = *(const bf16x8*)&sQe[(tt*16+lm)*136 + ks*32 + quad*8];
    }
    f32x4 a1;
    #pragma unroll
    for (int r=0;r<4;++r) a1[r] = 0.f;
    #pragma unroll
    for (int ks=0; ks<4; ++ks){
      bf16x8 kfr = *(const bf16x8*)&sKe[(nt*16+lm)*136 + ks*32 + quad*8];
      a1 = __builtin_amdgcn_mfma_f32_16x16x32_bf16(qf[mt][ks], kfr, a1, 0, 0, 0);
    }
    f32x4 ot[2][2];
    #pragma unroll
    for (int vh=0; vh<2; ++vh)
      #pragma unroll
      for (int tt=0; tt<2; ++tt)
        #pragma unroll
        for (int r=0;r<4;++r) ot[vh][tt][r] = 0.f;
    #pragma unroll
    for (int ks=0; ks<4; ++ks){
      #pragma unroll
      for (int vh=0; vh<2; ++vh){
        bf16x8 stf = *(const bf16x8*)&sST[(vh*64 + w*16+lm)*136 + ks*32 + quad*8];
        #pragma unroll
        for (int tt=0; tt<2; ++tt)
          ot[vh][tt] = __builtin_amdgcn_mfma_f32_16x16x32_bf16(stf, qf[tt][ks], ot[vh][tt], 0, 0, 0);
      }
    }
    #pragma unroll
    for (int r=0;r<4;++r){
      int t = mt*16 + quad*4 + r, s = nt*16 + lm;
      sP[t*40 + s] = f2b((s <= t) ? a1[r] : 0.f);
    }
    __syncthreads();
    // ---- phase2: S' = eb*(S + VT.KeT^T) ; oT += VT.P^T ; direct o store ----
    bf16x8 vta[2];
    vta[0] = *(const bf16x8*)&sVT[(w*16+lm)*40 + quad*8];
    vta[1] = *(const bf16x8*)&sVT[(64 + w*16+lm)*40 + quad*8];
    #pragma unroll
    for (int dt=0; dt<8; ++dt){
      bf16x8 kt = *(const bf16x8*)&sKeT[(dt*16+lm)*40 + quad*8];
      float eb = sEb[dt*16 + lm];
      #pragma unroll
      for (int vh=0; vh<2; ++vh){
        Sreg[vh][dt] = __builtin_amdgcn_mfma_f32_16x16x32_bf16(vta[vh], kt, Sreg[vh][dt], 0, 0, 0);
        #pragma unroll
        for (int r=0;r<4;++r) Sreg[vh][dt][r] *= eb;
      }
    }
    // sST mirror: sigma cols lm*8+dt contiguous over dt -> b128 writes
    #pragma unroll
    for (int vh=0; vh<2; ++vh){
      #pragma unroll
      for (int r=0;r<4;++r){
        uint4 pkv;
        pkv.x = (unsigned)f2b(Sreg[vh][0][r]) | ((unsigned)f2b(Sreg[vh][1][r]) << 16);
        pkv.y = (unsigned)f2b(Sreg[vh][2][r]) | ((unsigned)f2b(Sreg[vh][3][r]) << 16);
        pkv.z = (unsigned)f2b(Sreg[vh][4][r]) | ((unsigned)f2b(Sreg[vh][5][r]) << 16);
        pkv.w = (unsigned)f2b(Sreg[vh][6][r]) | ((unsigned)f2b(Sreg[vh][7][r]) << 16);
        *(uint4*)&sST[(vh*64 + w*16 + quad*4 + r)*136 + lm*8] = pkv;
      }
    }
    #pragma unroll
    for (int tt=0; tt<2; ++tt){
      bf16x8 pf = *(const bf16x8*)&sP[(tt*16+lm)*40 + quad*8];
      int p = c*CH2 + tt*16 + lm;
      int n = dir ? (SEQN-1-p) : p;
      #pragma unroll
      for (int vh=0; vh<2; ++vh){
        ot[vh][tt] = __builtin_amdgcn_mfma_f32_16x16x32_bf16(vta[vh], pf, ot[vh][tt], 0, 0, 0);
        ushort4 o4;
        o4.x = f2b(ot[vh][tt][0]); o4.y = f2b(ot[vh][tt][1]);
        o4.z = f2b(ot[vh][tt][2]); o4.w = f2b(ot[vh][tt][3]);
        *(ushort4*)&og[ogBase + (size_t)n*HV + vp*128 + vh*64 + w*16 + quad*4] = o4;
      }
    }
    __syncthreads();
  } // chunks
}

// ---------------- rmsnorm(f)+rmsnorm(b), gate with silu(g) ----------------
__global__ __launch_bounds__(256) void k_gate(const unsigned short* __restrict__ og,
                                              const unsigned short* __restrict__ g,
                                              const float* __restrict__ gnw,
                                              const float* __restrict__ lnw,
                                              unsigned short* __restrict__ y){
  int tok = blockIdx.x;
  int bb = tok / SEQN, n = tok % SEQN;
  int hh = threadIdx.x >> 6, l = threadIdx.x & 63;
  int j4 = l << 2;
  size_t basef = ((size_t)((0*BBATCH+bb)*NHEADS+hh))*SEQN*HV + (size_t)n*HV + j4;
  size_t baseb = ((size_t)((1*BBATCH+bb)*NHEADS+hh))*SEQN*HV + (size_t)n*HV + j4;
  ushort4 ofu = *(const ushort4*)&og[basef];
  ushort4 obu = *(const ushort4*)&og[baseb];
  float of0=b2f(ofu.x), of1=b2f(ofu.y), of2=b2f(ofu.z), of3=b2f(ofu.w);
  float ob0=b2f(obu.x), ob1=b2f(obu.y), ob2=b2f(obu.z), ob3=b2f(obu.w);
  float ssf = of0*of0 + of1*of1 + of2*of2 + of3*of3;
  float ssb = ob0*ob0 + ob1*ob1 + ob2*ob2 + ob3*ob3;
  #pragma unroll
  for (int m=32;m>=1;m>>=1){ ssf += __shfl_xor(ssf,m,64); ssb += __shfl_xor(ssb,m,64); }
  float rf = rsqrtf(ssf*(1.f/HV) + 1e-5f);
  float rb = rsqrtf(ssb*(1.f/HV) + 1e-5f);
  float4 gn = *(const float4*)&gnw[j4];
  float4 ln = *(const float4*)&lnw[j4];
  ushort4 gvu = *(const ushort4*)&g[(size_t)tok*1024 + hh*HV + j4];  // silu already applied
  float g0=b2f(gvu.x), g1=b2f(gvu.y), g2=b2f(gvu.z), g3=b2f(gvu.w);
  ushort4 out;
  out.x = f2b(g0*(of0*rf*gn.x + ob0*rb*ln.x));
  out.y = f2b(g1*(of1*rf*gn.y + ob1*rb*ln.y));
  out.z = f2b(g2*(of2*rf*gn.z + ob2*rb*ln.z));
  out.w = f2b(g3*(of3*rf*gn.w + ob3*rb*ln.w));
  *(ushort4*)&y[(size_t)tok*1024 + hh*HV + j4] = out;
}

extern "C" void kernel_launch(void* const* d_in, const int* in_sizes, int n_in,
                              void* d_out, int out_size, void* d_ws, size_t ws_size,
                              hipStream_t stream){
  (void)in_sizes; (void)n_in; (void)out_size;
  const float* x    = (const float*)d_in[0];
  const float* cw   = (const float*)d_in[1];
  const float* qkvw = (const float*)d_in[2];
  const float* gkw1 = (const float*)d_in[3];
  const float* gkw2 = (const float*)d_in[4];
  const float* gkb2 = (const float*)d_in[5];
  const float* gw   = (const float*)d_in[6];
  const float* gb   = (const float*)d_in[7];
  const float* gnw  = (const float*)d_in[8];
  const float* lnw  = (const float*)d_in[9];
  const float* ow   = (const float*)d_in[10];

  // Workspace layout (bytes), total 232,816,640 (proven budget):
  //   qkv  bf16 [25088,2048] @ 0 (103 MB) — prep overwrites q/k (sigma); after gla3 qkv dead:
  //        y @ qkv+0 (51.4MB), g @ qkv+51380224 (51.4MB)
  //   og   bf16 [2,8,4,3136,256] @ 102760448 (103 MB)
  //        pre-gla3 overlays: dSseg fp32 [6,256,64,128] @ +0 (50.3 MB, written by gla_state
  //        after zbuf dead), zbuf @ +25690112 (dead after prep), wqb @ +77070336, wc @ +80216064
  //        (both dead after GEMMs, before gla_state writes reach them... dSseg ends at 50.3MB ✓).
  //        wob @ +0 after k_gate.
  //   dbuf fp16 exp(delta) sigma [25088,512] @ 205520896 (25.7 MB) — dead after gla3;
  //        wgb bf16 [1024,512] @ 205520896 written AFTER gla3 (1 MB)
  //   ebF/ebB fp16 @ 231211008 / 232013824
  // d_out (51.38 MB): xs @ 0 (25.69 MB, live until g-GEMM); dSf fp32 [3,256,64,128]
  //   @ 25690112 (25.17 MB, ends 50855936 ≤ 51380224 ✓)
  if (ws_size < 232816640u) return;
  char* wsb = (char*)d_ws;
  char* dob = (char*)d_out;
  unsigned short* qkv  = (unsigned short*)(wsb + 0);
  unsigned short* g    = (unsigned short*)(wsb + 51380224);
  unsigned short* og   = (unsigned short*)(wsb + 102760448);
  float*          dSseg= (float*)(wsb + 102760448);
  unsigned short* zbuf = (unsigned short*)(wsb + 102760448 + 25690112);
  unsigned short* wqb  = (unsigned short*)(wsb + 102760448 + 77070336);
  unsigned short* wc   = (unsigned short*)(wsb + 102760448 + 80216064);
  unsigned short* dbuf = (unsigned short*)(wsb + 205520896);
  unsigned short* wgb  = (unsigned short*)(wsb + 205520896);   // overwrites dbuf AFTER gla3
  unsigned short* ebF  = (unsigned short*)(wsb + 231211008);
  unsigned short* ebB  = (unsigned short*)(wsb + 232013824);
  unsigned short* xs   = (unsigned short*)(dob + 0);
  float*          dSf  = (float*)(dob + 25690112);
  unsigned short* wob  = og;                         // after k_gate, og dead
  unsigned short* y    = qkv;                        // qkv dead after k_gla3
  float*          outp = (float*)d_out;

  k_conv_silu<<<NTOK*128/256, 256, 0, stream>>>(x, cw, xs);
  k_w2b<<<1024, 256, 0, stream>>>(qkvw, wqb, 2048*512);
  k_wc<<<2048, 256, 0, stream>>>(gkw1, gkw2, wc);
  k_gemm_mfma<0,1><<<dim3(16,196), 256, 0, stream>>>(xs, wqb, nullptr, qkv,  NTOK, 2048, 512);
  k_gemm_mfma<0,1><<<dim3(8,196),  256, 0, stream>>>(xs, wc,  gkb2,    zbuf, NTOK, 1024, 512);
  k_prep<<<BBATCH*NC2, 256, 0, stream>>>(qkv, zbuf, dbuf, ebF, ebB);
  k_gla_state<<<1536, 256, 0, stream>>>(qkv, dbuf, ebF, ebB, dSseg);
  k_gla_comb<<<256, 256, 0, stream>>>(dSseg, dSf, ebF, ebB);
  k_gla3<<<512, 256, 0, stream>>>(qkv, dbuf, ebF, ebB, og, dSf);
  k_w2b<<<512,  256, 0, stream>>>(gw, wgb, 1024*512);                      // dbuf dead now
  k_gemm_mfma<1,1><<<dim3(8,196),  256, 0, stream>>>(xs, wgb, gb, g, NTOK, 1024, 512);
  k_gate<<<NTOK, 256, 0, stream>>>(og, g, gnw, lnw, y);
  k_w2b<<<512, 256, 0, stream>>>(ow, wob, 512*1024);
  k_gemm_mfma<0,0><<<dim3(4,196), 256, 0, stream>>>(y, wob, nullptr, outp, NTOK, 512, 1024);
}

// Round 8
// 1083.813 us; speedup vs baseline: 1.4142x; 1.0470x over previous
//
#include <hip/hip_runtime.h>
#include <hip/hip_bf16.h>
#include <math.h>

#define NHEADS 4
#define DMODEL 512
#define HQK 128
#define HV 256
#define BBATCH 8
#define SH 56
#define SWW 56
#define SEQN (SH*SWW)          // 3136
#define NTOK (BBATCH*SEQN)     // 25088
#define CH2 32
#define NC2 (SEQN/CH2)         // 98

// sigma column permutation within each 128-col head: sigma(d) = (d&15)*8 + (d>>4).
// q/k/dbuf are stored sigma-permuted by k_prep; V, eb tables, dS stay natural.

typedef __bf16 bf16x8 __attribute__((ext_vector_type(8)));
typedef float  f32x4  __attribute__((ext_vector_type(4)));

__device__ __forceinline__ float silu_f(float v){ return v / (1.f + __expf(-v)); }

__device__ __forceinline__ float b2f(unsigned short u){
  union { unsigned int i; float f; } c; c.i = ((unsigned int)u) << 16; return c.f;
}
__device__ __forceinline__ unsigned short f2b(float f){
  __bf16 h = (__bf16)f;
  unsigned short u; __builtin_memcpy(&u, &h, 2); return u;
}
__device__ __forceinline__ float h2f(unsigned short u){
  _Float16 h; __builtin_memcpy(&h, &u, 2); return (float)h;
}
__device__ __forceinline__ unsigned short f2h(float f){
  _Float16 h = (_Float16)f; unsigned short u; __builtin_memcpy(&u, &h, 2); return u;
}
__device__ __forceinline__ float lsig16(float z){          // logsigmoid(z)/16
  float e = __expf(-fabsf(z));
  return (fminf(z, 0.f) - __logf(1.f + e)) * 0.0625f;
}
__device__ __forceinline__ void up8(uint4 v, unsigned short* o){
  o[0]=(unsigned short)v.x; o[1]=(unsigned short)(v.x>>16);
  o[2]=(unsigned short)v.y; o[3]=(unsigned short)(v.y>>16);
  o[4]=(unsigned short)v.z; o[5]=(unsigned short)(v.z>>16);
  o[6]=(unsigned short)v.w; o[7]=(unsigned short)(v.w>>16);
}
__device__ __forceinline__ uint4 pk8(const unsigned short* s){
  uint4 v;
  v.x = (unsigned)s[0] | ((unsigned)s[1]<<16);
  v.y = (unsigned)s[2] | ((unsigned)s[3]<<16);
  v.z = (unsigned)s[4] | ((unsigned)s[5]<<16);
  v.w = (unsigned)s[6] | ((unsigned)s[7]<<16);
  return v;
}

#define GLL16(gp, lp) __builtin_amdgcn_global_load_lds( \
    (const __attribute__((address_space(1))) unsigned int*)(gp), \
    (__attribute__((address_space(3))) unsigned int*)(lp), 16, 0, 0)

// ---------------- fp32 -> bf16 weight conversion ----------------
__global__ __launch_bounds__(256) void k_w2b(const float* __restrict__ w,
                                             unsigned short* __restrict__ o, int n){
  int i = (blockIdx.x*256 + threadIdx.x) << 2;
  if (i >= n) return;
  float4 v = *(const float4*)&w[i];
  ushort4 p;
  p.x = f2b(v.x); p.y = f2b(v.y); p.z = f2b(v.z); p.w = f2b(v.w);
  *(ushort4*)&o[i] = p;
}

// ---------------- Wc = gk_w2[1024,16] @ gk_w1[16,512] -> bf16 [1024][512] ----------------
__global__ __launch_bounds__(256) void k_wc(const float* __restrict__ w1,
                                            const float* __restrict__ w2,
                                            unsigned short* __restrict__ wc){
  int idx = blockIdx.x*256 + threadIdx.x;   // n*512 + k
  int n = idx >> 9, k = idx & 511;
  float acc = 0.f;
  #pragma unroll
  for (int r=0;r<16;++r) acc += w2[n*16+r]*w1[r*512+k];
  wc[idx] = f2b(acc);
}

// ---------------- conv 3x3 depthwise + SiLU -> xs (bf16) ----------------
__global__ __launch_bounds__(256) void k_conv_silu(const float* __restrict__ x,
                                                   const float* __restrict__ cw,
                                                   unsigned short* __restrict__ xs){
  int gid = blockIdx.x*256 + threadIdx.x;     // NTOK*128 threads
  int c4  = (gid & 127) << 2;
  int tok = gid >> 7;
  int b = tok / SEQN, sp = tok % SEQN;
  int hh = sp / SWW, ww = sp % SWW;
  float a0=0.f,a1=0.f,a2=0.f,a3=0.f;
  #pragma unroll
  for (int dh=-1; dh<=1; ++dh){
    int h2 = hh+dh; if (h2<0||h2>=SH) continue;
    #pragma unroll
    for (int dw=-1; dw<=1; ++dw){
      int w2 = ww+dw; if (w2<0||w2>=SWW) continue;
      const float4 xv = *(const float4*)&x[((size_t)(b*SEQN + h2*SWW + w2))*DMODEL + c4];
      int tap = (dh+1)*3 + (dw+1);
      a0 += xv.x * cw[(c4+0)*9 + tap];
      a1 += xv.y * cw[(c4+1)*9 + tap];
      a2 += xv.z * cw[(c4+2)*9 + tap];
      a3 += xv.w * cw[(c4+3)*9 + tap];
    }
  }
  ushort4 o;
  o.x = f2b(silu_f(a0)); o.y = f2b(silu_f(a1)); o.z = f2b(silu_f(a2)); o.w = f2b(silu_f(a3));
  *(ushort4*)&xs[(size_t)tok*DMODEL + c4] = o;
}

// ------- MFMA GEMM: C[M,N] = act(A_bf16[M,K] * W_bf16[N,K]^T + bias) -------
// XCD-aware block swizzle (T1): consecutive M-tiles (sharing A-panels) land on one XCD's L2.
// Bijective since nwg % 8 == 0 for all grids used here.
template<int ACT, int CBF>
__global__ __launch_bounds__(256) void k_gemm_mfma(const unsigned short* __restrict__ A,
                                                   const unsigned short* __restrict__ W,
                                                   const float* __restrict__ bias,
                                                   void* __restrict__ Cv,
                                                   int M, int N, int K){
  __shared__ unsigned short sA[128*32];
  __shared__ unsigned short sB[128*32];
  const int tid  = threadIdx.x;
  const int wave = tid >> 6, lane = tid & 63;
  const int lm = lane & 15, quad = lane >> 4;
  const int wm = wave & 1, wn = wave >> 1;
  const int nwg = gridDim.x * gridDim.y;
  const int hb  = blockIdx.y * gridDim.x + blockIdx.x;
  const int fb  = (hb & 7) * (nwg >> 3) + (hb >> 3);
  const int m0 = (fb / gridDim.x) * 128, n0 = (fb % gridDim.x) * 128;

  const int r0 = tid >> 2,  c0 = (tid & 3) << 3;
  const int f1 = tid + 256;
  const int r1 = f1 >> 2,   c1 = (f1 & 3) << 3;

  f32x4 acc[4][4] = {};

  for (int kt = 0; kt < K; kt += 32){
    GLL16(&A[(size_t)(m0 + r0)*K + kt + c0], &sA[(size_t)tid*8]);
    GLL16(&A[(size_t)(m0 + r1)*K + kt + c1], &sA[(size_t)f1*8]);
    GLL16(&W[(size_t)(n0 + r0)*K + kt + c0], &sB[(size_t)tid*8]);
    GLL16(&W[(size_t)(n0 + r1)*K + kt + c1], &sB[(size_t)f1*8]);
    __syncthreads();
    bf16x8 af[4], bf[4];
    #pragma unroll
    for (int i=0;i<4;++i) af[i] = *(const bf16x8*)&sA[(wm*64 + i*16 + lm)*32 + quad*8];
    #pragma unroll
    for (int j=0;j<4;++j) bf[j] = *(const bf16x8*)&sB[(wn*64 + j*16 + lm)*32 + quad*8];
    #pragma unroll
    for (int i=0;i<4;++i)
      #pragma unroll
      for (int j=0;j<4;++j)
        acc[i][j] = __builtin_amdgcn_mfma_f32_16x16x32_bf16(af[i], bf[j], acc[i][j], 0, 0, 0);
    __syncthreads();
  }

  #pragma unroll
  for (int i=0;i<4;++i){
    #pragma unroll
    for (int r=0;r<4;++r){
      size_t m = (size_t)(m0 + wm*64 + i*16 + quad*4 + r);
      #pragma unroll
      for (int j=0;j<4;++j){
        int n = n0 + wn*64 + j*16 + lm;
        float v = acc[i][j][r];
        if (bias) v += bias[n];
        if (ACT==1) v = silu_f(v);
        if (CBF) ((unsigned short*)Cv)[m*(size_t)N + n] = f2b(v);
        else     ((float*)Cv)[m*(size_t)N + n] = v;
      }
    }
  }
}

// ---------------- prep: gates -> qe_f/ke_f in-place (SIGMA-permuted cols), exp(delta) fp16
// (sigma-permuted), eb tables (natural d). Verified R6/R7 (absmax bit-identical).
__global__ __launch_bounds__(256) void k_prep(unsigned short* __restrict__ qkv,
                                              const unsigned short* __restrict__ z,
                                              unsigned short* __restrict__ dbuf,
                                              unsigned short* __restrict__ ebF,
                                              unsigned short* __restrict__ ebB){
  const int blk = blockIdx.x;
  const int bb = blk / NC2, cB = blk % NC2;
  const int j  = threadIdx.x << 1;                // sigma col pair (even), 0..510
  const int cb = j & 0x180;                       // head base = hh*128
  const int sl = j & 127;
  const int d1 = ((sl & 7) << 4) | (sl >> 3);     // natural col for sigma col sl
  const int d2 = d1 + 16;                         // natural col for sigma col sl+1
  const size_t base = (size_t)bb*SEQN + cB*CH2;
  const float sc = 0.08838834764831845f;          // 128^-0.5
  float bf0[CH2], bf1[CH2];
  float r0 = 0.f, r1 = 0.f;
  #pragma unroll
  for (int t=0;t<CH2;++t){
    size_t tok = base + t;
    float z0 = b2f(z[tok*1024 + cb + d1]);
    float z1 = b2f(z[tok*1024 + cb + d2]);
    r0 += lsig16(z0);
    r1 += lsig16(z1);
    bf0[t] = r0; bf1[t] = r1;
    float qv1 = b2f(qkv[tok*2048 + cb + d1]);
    float qv2 = b2f(qkv[tok*2048 + cb + d2]);
    float kv1 = b2f(qkv[tok*2048 + 512 + cb + d1]);
    float kv2 = b2f(qkv[tok*2048 + 512 + cb + d2]);
    float e0 = __expf(r0),  e1 = __expf(r1);
    float n0 = __expf(-r0), n1 = __expf(-r1);
    unsigned qo = (unsigned)f2b(qv1*e0*sc) | ((unsigned)f2b(qv2*e1*sc) << 16);
    unsigned ko = (unsigned)f2b(kv1*n0)    | ((unsigned)f2b(kv2*n1) << 16);
    __syncthreads();   // all reads of token t done before any permuted write of token t
    *(unsigned*)&qkv[tok*2048 + j] = qo;
    *(unsigned*)&qkv[tok*2048 + 512 + j] = ko;
  }
  const int hh = j >> 7;
  {
    int ef = ((bb*NHEADS + hh)*NC2 + cB)*HQK;
    ebF[ef + d1] = f2h(__expf(bf0[CH2-1]));
    ebF[ef + d2] = f2h(__expf(bf1[CH2-1]));
  }
  r0 = 0.f; r1 = 0.f;
  #pragma unroll
  for (int t=CH2-1;t>=0;--t){
    size_t tok = base + t;
    float z0 = b2f(z[tok*1024 + 512 + cb + d1]);
    float z1 = b2f(z[tok*1024 + 512 + cb + d2]);
    r0 += lsig16(z0);
    r1 += lsig16(z1);
    float dd0 = r0 - bf0[t], dd1 = r1 - bf1[t];
    *(unsigned*)&dbuf[tok*512 + j] = (unsigned)f2h(__expf(dd0))
                                   | ((unsigned)f2h(__expf(dd1)) << 16);
  }
  {
    int eb = ((bb*NHEADS + hh)*NC2 + (NC2-1-cB))*HQK;
    ebB[eb + d1] = f2h(__expf(r0));
    ebB[eb + d2] = f2h(__expf(r1));
  }
}

// sigma-load -> sKeT[d][t] mapping: thread loads 16B pairs at sigma offset o8*16 (+8).
#define SKET_STORE(sKeT_, kb_, o8_, ts_) \
  _Pragma("unroll") \
  for (int u=0;u<8;++u){ \
    (sKeT_)[(u*16 + 2*(o8_)    )*40 + (ts_)] = (kb_)[u]; \
    (sKeT_)[(u*16 + 2*(o8_) + 1)*40 + (ts_)] = (kb_)[u+8]; \
  }

// ---------------- GLA state-only pass: DeltaS over sub-segments of the first 74 chunks --------
// grid = 768: bx = seg*128 + combo; combo = vp | dir<<1 | hh<<2 | bb<<4; seg 0..5 covers
// [0,13),[13,25),[25,37),[37,50),[50,62),[62,74). v-width 128 (vp-merged), double-buffered
// LDS (42 KB -> 3 blocks/CU), ONE barrier per chunk (next-chunk staging overlaps MFMA).
// Writes dSseg in the old 256-combo convention (vq = vp*2+vh) so comb/gla3 are unchanged.
__global__ __launch_bounds__(256,3) void k_gla_state(const unsigned short* __restrict__ qkvb,
                                                     const unsigned short* __restrict__ dbuf,
                                                     const unsigned short* __restrict__ ebFt,
                                                     const unsigned short* __restrict__ ebBt,
                                                     float* __restrict__ dSseg){
  __shared__ __align__(16) unsigned short sKeT[2][128*40];  // [buf][d][t] stride 40
  __shared__ __align__(16) unsigned short sVT[2][128*40];   // [buf][v128][t]
  __shared__ float sEb[2][128];

  const int tid = threadIdx.x;
  const int bx = blockIdx.x;
  const int combo = bx & 127, seg = bx >> 7;
  const int vp = combo & 1, dir = (combo>>1)&1, hh = (combo>>2)&3, bb = (combo>>4)&7;

  const int w = tid >> 6, lane = tid & 63;
  const int quad = lane >> 4, lm = lane & 15;
  const int ts = tid >> 3, o8 = tid & 7, d16 = o8 << 4;
  const int tl = tid & 31, vg = tid >> 5;

  const int kcol = 512 + hh*HQK, vcol = 1024 + hh*HV + vp*128;
  const int dcol = hh*HQK;
  const unsigned short* ebT = dir ? ebBt : ebFt;
  const int ebBase = (bb*NHEADS + hh)*NC2*HQK;
  const int c0 = (seg==0)?0:(seg==1)?13:(seg==2)?25:(seg==3)?37:(seg==4)?50:62;
  const int c1 = (seg==0)?13:(seg==1)?25:(seg==2)?37:(seg==3)?50:(seg==4)?62:74;

#define STSTAGE(c_, bi_) { \
    int p_ = (c_)*CH2 + ts; \
    int n_ = dir ? (SEQN-1-p_) : p_; \
    size_t tok_ = (size_t)bb*SEQN + n_; \
    uint4 k0_ = *(const uint4*)&qkvb[tok_*2048 + kcol + d16]; \
    uint4 k1_ = *(const uint4*)&qkvb[tok_*2048 + kcol + d16 + 8]; \
    unsigned short kb_[16]; \
    up8(k0_, kb_); up8(k1_, kb_+8); \
    if (dir){ \
      uint4 dd0_ = *(const uint4*)&dbuf[tok_*512 + dcol + d16]; \
      uint4 dd1_ = *(const uint4*)&dbuf[tok_*512 + dcol + d16 + 8]; \
      unsigned short eh_[16]; \
      up8(dd0_, eh_); up8(dd1_, eh_+8); \
      _Pragma("unroll") \
      for (int u=0;u<16;++u) \
        kb_[u] = f2b(b2f(kb_[u]) * __builtin_amdgcn_rcpf(h2f(eh_[u]))); \
    } \
    SKET_STORE(sKeT[bi_], kb_, o8, ts); \
    int pv_ = (c_)*CH2 + tl; \
    int nv_ = dir ? (SEQN-1-pv_) : pv_; \
    size_t tokv_ = (size_t)bb*SEQN + nv_; \
    uint4 uv0_ = *(const uint4*)&qkvb[tokv_*2048 + vcol + vg*8]; \
    uint4 uv1_ = *(const uint4*)&qkvb[tokv_*2048 + vcol + 64 + vg*8]; \
    unsigned short su_[8]; \
    up8(uv0_, su_); \
    _Pragma("unroll") \
    for (int u=0;u<8;++u) sVT[bi_][(vg*8+u)*40 + tl] = su_[u]; \
    up8(uv1_, su_); \
    _Pragma("unroll") \
    for (int u=0;u<8;++u) sVT[bi_][(64+vg*8+u)*40 + tl] = su_[u]; \
    if (tid < 128) sEb[bi_][tid] = h2f(ebT[ebBase + (c_)*HQK + tid]); \
  }

  f32x4 Sreg[2][8];
  #pragma unroll
  for (int vh=0; vh<2; ++vh)
    #pragma unroll
    for (int i=0;i<8;++i)
      #pragma unroll
      for (int r=0;r<4;++r) Sreg[vh][i][r] = 0.f;

  STSTAGE(c0, 0);
  __syncthreads();
  for (int c = c0; c < c1; ++c){
    const int cur = (c - c0) & 1;
    if (c + 1 < c1) STSTAGE(c+1, cur^1);
    bf16x8 vta0 = *(const bf16x8*)&sVT[cur][(w*16+lm)*40 + quad*8];
    bf16x8 vta1 = *(const bf16x8*)&sVT[cur][(64 + w*16+lm)*40 + quad*8];
    #pragma unroll
    for (int dt=0; dt<8; ++dt){
      bf16x8 kt = *(const bf16x8*)&sKeT[cur][(dt*16+lm)*40 + quad*8];
      float eb = sEb[cur][dt*16 + lm];
      Sreg[0][dt] = __builtin_amdgcn_mfma_f32_16x16x32_bf16(vta0, kt, Sreg[0][dt], 0, 0, 0);
      Sreg[1][dt] = __builtin_amdgcn_mfma_f32_16x16x32_bf16(vta1, kt, Sreg[1][dt], 0, 0, 0);
      #pragma unroll
      for (int r=0;r<4;++r){ Sreg[0][dt][r] *= eb; Sreg[1][dt][r] *= eb; }
    }
    __syncthreads();
  }
#undef STSTAGE

  #pragma unroll
  for (int vh=0; vh<2; ++vh){
    const int combo_s = (vp*2+vh) | (dir<<2) | (hh<<3) | (bb<<5);
    const size_t sbase = ((size_t)seg*256 + combo_s) * 8192;
    #pragma unroll
    for (int dt=0; dt<8; ++dt){
      #pragma unroll
      for (int r=0;r<4;++r)
        dSseg[sbase + (size_t)(w*16 + quad*4 + r)*128 + dt*16 + lm] = Sreg[vh][dt][r];
    }
  }
}

// ---------------- combine sub-segments into S25, S50, S74 ----------------
// grid = 256 (combo), 256 threads.
// S25 = D1*d0 + d1 ; S50 = D3*(D2*S25 + d2) + d3 ; S74 = D5*(D4*S50 + d4) + d5
__global__ __launch_bounds__(256) void k_gla_comb(const float* __restrict__ dSseg,
                                                  float* __restrict__ dSf,
                                                  const unsigned short* __restrict__ ebFt,
                                                  const unsigned short* __restrict__ ebBt){
  const int combo = blockIdx.x;
  const int dir = (combo>>2)&1, hh = (combo>>3)&3, bb = (combo>>5)&7;
  const unsigned short* ebT = dir ? ebBt : ebFt;
  const int ebBase = (bb*NHEADS + hh)*NC2*HQK;
  const int t = threadIdx.x;
  const int d0 = (t << 2) & 127;
  float D1[4]={1,1,1,1}, D2[4]={1,1,1,1}, D3[4]={1,1,1,1}, D4[4]={1,1,1,1}, D5[4]={1,1,1,1};
  for (int c=13; c<25; ++c){
    ushort4 ev = *(const ushort4*)&ebT[ebBase + c*HQK + d0];
    D1[0]*=h2f(ev.x); D1[1]*=h2f(ev.y); D1[2]*=h2f(ev.z); D1[3]*=h2f(ev.w);
  }
  for (int c=25; c<37; ++c){
    ushort4 ev = *(const ushort4*)&ebT[ebBase + c*HQK + d0];
    D2[0]*=h2f(ev.x); D2[1]*=h2f(ev.y); D2[2]*=h2f(ev.z); D2[3]*=h2f(ev.w);
  }
  for (int c=37; c<50; ++c){
    ushort4 ev = *(const ushort4*)&ebT[ebBase + c*HQK + d0];
    D3[0]*=h2f(ev.x); D3[1]*=h2f(ev.y); D3[2]*=h2f(ev.z); D3[3]*=h2f(ev.w);
  }
  for (int c=50; c<62; ++c){
    ushort4 ev = *(const ushort4*)&ebT[ebBase + c*HQK + d0];
    D4[0]*=h2f(ev.x); D4[1]*=h2f(ev.y); D4[2]*=h2f(ev.z); D4[3]*=h2f(ev.w);
  }
  for (int c=62; c<74; ++c){
    ushort4 ev = *(const ushort4*)&ebT[ebBase + c*HQK + d0];
    D5[0]*=h2f(ev.x); D5[1]*=h2f(ev.y); D5[2]*=h2f(ev.z); D5[3]*=h2f(ev.w);
  }
  const size_t bA = (size_t)combo*8192;
  const size_t SEG = (size_t)256*8192;
  #pragma unroll
  for (int r=0;r<8;++r){
    int idx = r*1024 + (t<<2);
    float4 a0 = *(const float4*)&dSseg[bA + idx];
    float4 a1 = *(const float4*)&dSseg[bA + SEG + idx];
    float4 a2 = *(const float4*)&dSseg[bA + 2*SEG + idx];
    float4 a3 = *(const float4*)&dSseg[bA + 3*SEG + idx];
    float4 a4 = *(const float4*)&dSseg[bA + 4*SEG + idx];
    float4 a5 = *(const float4*)&dSseg[bA + 5*SEG + idx];
    float4 s25, s50, s74;
    s25.x = D1[0]*a0.x + a1.x; s25.y = D1[1]*a0.y + a1.y;
    s25.z = D1[2]*a0.z + a1.z; s25.w = D1[3]*a0.w + a1.w;
    s50.x = D3[0]*(D2[0]*s25.x + a2.x) + a3.x;
    s50.y = D3[1]*(D2[1]*s25.y + a2.y) + a3.y;
    s50.z = D3[2]*(D2[2]*s25.z + a2.z) + a3.z;
    s50.w = D3[3]*(D2[3]*s25.w + a2.w) + a3.w;
    s74.x = D5[0]*(D4[0]*s50.x + a4.x) + a5.x;
    s74.y = D5[1]*(D4[1]*s50.y + a4.y) + a5.y;
    s74.z = D5[2]*(D4[2]*s50.z + a4.z) + a5.z;
    s74.w = D5[3]*(D4[3]*s50.w + a4.w) + a5.w;
    *(float4*)&dSf[bA + idx] = s25;
    *(float4*)&dSf[SEG + bA + idx] = s50;
    *(float4*)&dSf[2*SEG + bA + idx] = s74;
  }
}

// ---------------- GLA chunked scan, vq-MERGED (v-width 128), quarter-sequence per block ------
// grid = 512: bx = seg*128 + combo; combo = vp | dir<<1 | hh<<2 | bb<<4 (128 combos).
// seg 0: [0,25) from 0; seg 1: [25,50) from S25; seg 2: [50,74) from S50; seg 3: [74,98) from S74.
// LDS = 75,776 B -> 2 blocks/CU. Verified R7.
__global__ __launch_bounds__(256,2) void k_gla3(const unsigned short* __restrict__ qkvb,
                                                const unsigned short* __restrict__ dbuf,
                                                const unsigned short* __restrict__ ebFt,
                                                const unsigned short* __restrict__ ebBt,
                                                unsigned short* __restrict__ og,
                                                const float* __restrict__ dSf){
  __shared__ __align__(16) unsigned short sQe[32*136];    // [t][sigma-d]
  __shared__ __align__(16) unsigned short sKe[32*136];    // [t][sigma-d]
  __shared__ __align__(16) unsigned short sKeT[128*40];   // [d][t] natural d
  __shared__ __align__(16) unsigned short sVT[128*40];    // [v128][t]
  __shared__ __align__(16) unsigned short sST[128*136];   // [v128][sigma-d]
  __shared__ __align__(16) unsigned short sP[32*40];      // [t][s]
  __shared__ float sEb[128];

  const int tid = threadIdx.x;
  const int bx = blockIdx.x;
  const int combo = bx & 127, seg = bx >> 7;
  const int vp = combo & 1, dir = (combo>>1)&1, hh = (combo>>2)&3, bb = (combo>>4)&7;

  const int w = tid >> 6, lane = tid & 63;
  const int quad = lane >> 4, lm = lane & 15;
  const int mt = w >> 1, nt = w & 1;
  const int ts = tid >> 3, o8 = tid & 7, d16 = o8 << 4;  // qe/ke stage mapping
  const int tl = tid & 31, vg = tid >> 5;                // v stage mapping

  const int qcol = hh*HQK, kcol = 512 + hh*HQK, vcol = 1024 + hh*HV + vp*128;
  const int dcol = hh*HQK;
  const unsigned short* ebT = dir ? ebBt : ebFt;
  const int ebBase = (bb*NHEADS + hh)*NC2*HQK;
  const size_t ogBase = ((size_t)((dir*BBATCH + bb)*NHEADS + hh)) * SEQN * HV;

  f32x4 Sreg[2][8];
  #pragma unroll
  for (int vh=0; vh<2; ++vh)
    #pragma unroll
    for (int i=0;i<8;++i)
      #pragma unroll
      for (int r=0;r<4;++r) Sreg[vh][i][r] = 0.f;
  if (seg){
    #pragma unroll
    for (int vh=0; vh<2; ++vh){
      const int combo_s = (vp*2+vh) | (dir<<2) | (hh<<3) | (bb<<5);
      const size_t sbase = ((size_t)(seg-1)*256 + combo_s) * 8192;
      #pragma unroll
      for (int dt=0; dt<8; ++dt){
        #pragma unroll
        for (int r=0;r<4;++r){
          float sv = dSf[sbase + (size_t)(w*16 + quad*4 + r)*128 + dt*16 + lm];
          Sreg[vh][dt][r] = sv;
          sST[(vh*64 + w*16 + quad*4 + r)*136 + lm*8 + dt] = f2b(sv);
        }
      }
    }
  } else {
    for (int i = tid; i < 128*136; i += 256) sST[i] = 0;
  }
  __syncthreads();

  const int cBeg = (seg==0)?0:(seg==1)?25:(seg==2)?50:74;
  const int cEnd = (seg==0)?25:(seg==1)?50:(seg==2)?74:98;

  for (int c = cBeg; c < cEnd; ++c){
    // ---- stage qe/ke (+backward gate fixup), v (two 64-halves), eb ----
    {
      int p = c*CH2 + ts;
      int n = dir ? (SEQN-1-p) : p;
      size_t tok = (size_t)bb*SEQN + n;
      uint4 q0 = *(const uint4*)&qkvb[tok*2048 + qcol + d16];
      uint4 q1 = *(const uint4*)&qkvb[tok*2048 + qcol + d16 + 8];
      uint4 k0 = *(const uint4*)&qkvb[tok*2048 + kcol + d16];
      uint4 k1 = *(const uint4*)&qkvb[tok*2048 + kcol + d16 + 8];
      unsigned short kb[16];
      up8(k0, kb); up8(k1, kb+8);
      if (dir){
        uint4 dd0 = *(const uint4*)&dbuf[tok*512 + dcol + d16];
        uint4 dd1 = *(const uint4*)&dbuf[tok*512 + dcol + d16 + 8];
        unsigned short eh[16], qb[16];
        up8(dd0, eh); up8(dd1, eh+8);
        up8(q0, qb);  up8(q1, qb+8);
        #pragma unroll
        for (int u=0;u<16;++u){
          float e  = h2f(eh[u]);
          float ei = __builtin_amdgcn_rcpf(e);
          qb[u] = f2b(b2f(qb[u]) * e);
          kb[u] = f2b(b2f(kb[u]) * ei);
        }
        q0 = pk8(qb); q1 = pk8(qb+8);
        k0 = pk8(kb); k1 = pk8(kb+8);
      }
      *(uint4*)&sQe[ts*136 + d16]     = q0;
      *(uint4*)&sQe[ts*136 + d16 + 8] = q1;
      *(uint4*)&sKe[ts*136 + d16]     = k0;
      *(uint4*)&sKe[ts*136 + d16 + 8] = k1;
      SKET_STORE(sKeT, kb, o8, ts);
      int pv = c*CH2 + tl;
      int nv = dir ? (SEQN-1-pv) : pv;
      size_t tokv = (size_t)bb*SEQN + nv;
      uint4 uv0 = *(const uint4*)&qkvb[tokv*2048 + vcol + vg*8];
      uint4 uv1 = *(const uint4*)&qkvb[tokv*2048 + vcol + 64 + vg*8];
      unsigned short su[8];
      up8(uv0, su);
      #pragma unroll
      for (int u=0;u<8;++u) sVT[(vg*8+u)*40 + tl] = su[u];
      up8(uv1, su);
      #pragma unroll
      for (int u=0;u<8;++u) sVT[(64+vg*8+u)*40 + tl] = su[u];
    }
    if (tid < 128) sEb[tid] = h2f(ebT[ebBase + c*HQK + tid]);
    __syncthreads();
    // ---- phase1: A = Qe.Ke^T ; oT += ST.Qe^T (both v-halves) ; mask -> sP ----
    bf16x8 qf[2][4];
    #pragma unroll
    for (int tt=0; tt<2; ++tt){
      #pragma unroll
      for (int ks=0; ks<4; ++ks)
        qf[tt][ks] = *(const bf16x8*)&sQe[(tt*16+lm)*136 + ks*32 + quad*8];
    }
    f32x4 a1;
    #pragma unroll
    for (int r=0;r<4;++r) a1[r] = 0.f;
    #pragma unroll
    for (int ks=0; ks<4; ++ks){
      bf16x8 kfr = *(const bf16x8*)&sKe[(nt*16+lm)*136 + ks*32 + quad*8];
      a1 = __builtin_amdgcn_mfma_f32_16x16x32_bf16(qf[mt][ks], kfr, a1, 0, 0, 0);
    }
    f32x4 ot[2][2];
    #pragma unroll
    for (int vh=0; vh<2; ++vh)
      #pragma unroll
      for (int tt=0; tt<2; ++tt)
        #pragma unroll
        for (int r=0;r<4;++r) ot[vh][tt][r] = 0.f;
    #pragma unroll
    for (int ks=0; ks<4; ++ks){
      #pragma unroll
      for (int vh=0; vh<2; ++vh){
        bf16x8 stf = *(const bf16x8*)&sST[(vh*64 + w*16+lm)*136 + ks*32 + quad*8];
        #pragma unroll
        for (int tt=0; tt<2; ++tt)
          ot[vh][tt] = __builtin_amdgcn_mfma_f32_16x16x32_bf16(stf, qf[tt][ks], ot[vh][tt], 0, 0, 0);
      }
    }
    #pragma unroll
    for (int r=0;r<4;++r){
      int t = mt*16 + quad*4 + r, s = nt*16 + lm;
      sP[t*40 + s] = f2b((s <= t) ? a1[r] : 0.f);
    }
    __syncthreads();
    // ---- phase2: S' = eb*(S + VT.KeT^T) ; oT += VT.P^T ; direct o store ----
    bf16x8 vta[2];
    vta[0] = *(const bf16x8*)&sVT[(w*16+lm)*40 + quad*8];
    vta[1] = *(const bf16x8*)&sVT[(64 + w*16+lm)*40 + quad*8];
    #pragma unroll
    for (int dt=0; dt<8; ++dt){
      bf16x8 kt = *(const bf16x8*)&sKeT[(dt*16+lm)*40 + quad*8];
      float eb = sEb[dt*16 + lm];
      #pragma unroll
      for (int vh=0; vh<2; ++vh){
        Sreg[vh][dt] = __builtin_amdgcn_mfma_f32_16x16x32_bf16(vta[vh], kt, Sreg[vh][dt], 0, 0, 0);
        #pragma unroll
        for (int r=0;r<4;++r) Sreg[vh][dt][r] *= eb;
      }
    }
    // sST mirror: sigma cols lm*8+dt contiguous over dt -> b128 writes
    #pragma unroll
    for (int vh=0; vh<2; ++vh){
      #pragma unroll
      for (int r=0;r<4;++r){
        uint4 pkv;
        pkv.x = (unsigned)f2b(Sreg[vh][0][r]) | ((unsigned)f2b(Sreg[vh][1][r]) << 16);
        pkv.y = (unsigned)f2b(Sreg[vh][2][r]) | ((unsigned)f2b(Sreg[vh][3][r]) << 16);
        pkv.z = (unsigned)f2b(Sreg[vh][4][r]) | ((unsigned)f2b(Sreg[vh][5][r]) << 16);
        pkv.w = (unsigned)f2b(Sreg[vh][6][r]) | ((unsigned)f2b(Sreg[vh][7][r]) << 16);
        *(uint4*)&sST[(vh*64 + w*16 + quad*4 + r)*136 + lm*8] = pkv;
      }
    }
    #pragma unroll
    for (int tt=0; tt<2; ++tt){
      bf16x8 pf = *(const bf16x8*)&sP[(tt*16+lm)*40 + quad*8];
      int p = c*CH2 + tt*16 + lm;
      int n = dir ? (SEQN-1-p) : p;
      #pragma unroll
      for (int vh=0; vh<2; ++vh){
        ot[vh][tt] = __builtin_amdgcn_mfma_f32_16x16x32_bf16(vta[vh], pf, ot[vh][tt], 0, 0, 0);
        ushort4 o4;
        o4.x = f2b(ot[vh][tt][0]); o4.y = f2b(ot[vh][tt][1]);
        o4.z = f2b(ot[vh][tt][2]); o4.w = f2b(ot[vh][tt][3]);
        *(ushort4*)&og[ogBase + (size_t)n*HV + vp*128 + vh*64 + w*16 + quad*4] = o4;
      }
    }
    __syncthreads();
  } // chunks
}

// ---------------- rmsnorm(f)+rmsnorm(b), gate with silu(g) ----------------
__global__ __launch_bounds__(256) void k_gate(const unsigned short* __restrict__ og,
                                              const unsigned short* __restrict__ g,
                                              const float* __restrict__ gnw,
                                              const float* __restrict__ lnw,
                                              unsigned short* __restrict__ y){
  int tok = blockIdx.x;
  int bb = tok / SEQN, n = tok % SEQN;
  int hh = threadIdx.x >> 6, l = threadIdx.x & 63;
  int j4 = l << 2;
  size_t basef = ((size_t)((0*BBATCH+bb)*NHEADS+hh))*SEQN*HV + (size_t)n*HV + j4;
  size_t baseb = ((size_t)((1*BBATCH+bb)*NHEADS+hh))*SEQN*HV + (size_t)n*HV + j4;
  ushort4 ofu = *(const ushort4*)&og[basef];
  ushort4 obu = *(const ushort4*)&og[baseb];
  float of0=b2f(ofu.x), of1=b2f(ofu.y), of2=b2f(ofu.z), of3=b2f(ofu.w);
  float ob0=b2f(obu.x), ob1=b2f(obu.y), ob2=b2f(obu.z), ob3=b2f(obu.w);
  float ssf = of0*of0 + of1*of1 + of2*of2 + of3*of3;
  float ssb = ob0*ob0 + ob1*ob1 + ob2*ob2 + ob3*ob3;
  #pragma unroll
  for (int m=32;m>=1;m>>=1){ ssf += __shfl_xor(ssf,m,64); ssb += __shfl_xor(ssb,m,64); }
  float rf = rsqrtf(ssf*(1.f/HV) + 1e-5f);
  float rb = rsqrtf(ssb*(1.f/HV) + 1e-5f);
  float4 gn = *(const float4*)&gnw[j4];
  float4 ln = *(const float4*)&lnw[j4];
  ushort4 gvu = *(const ushort4*)&g[(size_t)tok*1024 + hh*HV + j4];  // silu already applied
  float g0=b2f(gvu.x), g1=b2f(gvu.y), g2=b2f(gvu.z), g3=b2f(gvu.w);
  ushort4 out;
  out.x = f2b(g0*(of0*rf*gn.x + ob0*rb*ln.x));
  out.y = f2b(g1*(of1*rf*gn.y + ob1*rb*ln.y));
  out.z = f2b(g2*(of2*rf*gn.z + ob2*rb*ln.z));
  out.w = f2b(g3*(of3*rf*gn.w + ob3*rb*ln.w));
  *(ushort4*)&y[(size_t)tok*1024 + hh*HV + j4] = out;
}

extern "C" void kernel_launch(void* const* d_in, const int* in_sizes, int n_in,
                              void* d_out, int out_size, void* d_ws, size_t ws_size,
                              hipStream_t stream){
  (void)in_sizes; (void)n_in; (void)out_size;
  const float* x    = (const float*)d_in[0];
  const float* cw   = (const float*)d_in[1];
  const float* qkvw = (const float*)d_in[2];
  const float* gkw1 = (const float*)d_in[3];
  const float* gkw2 = (const float*)d_in[4];
  const float* gkb2 = (const float*)d_in[5];
  const float* gw   = (const float*)d_in[6];
  const float* gb   = (const float*)d_in[7];
  const float* gnw  = (const float*)d_in[8];
  const float* lnw  = (const float*)d_in[9];
  const float* ow   = (const float*)d_in[10];

  // Workspace layout (bytes), total 232,816,640 (proven budget):
  //   qkv  bf16 [25088,2048] @ 0 (103 MB) — prep overwrites q/k (sigma); after gla3 qkv dead:
  //        y @ qkv+0 (51.4MB), g @ qkv+51380224 (51.4MB)
  //   og   bf16 [2,8,4,3136,256] @ 102760448 (103 MB)
  //        pre-gla3 overlays: dSseg fp32 [6,256,64,128] @ +0 (50.3 MB, written by gla_state
  //        after zbuf dead), zbuf @ +25690112 (dead after prep), wqb @ +77070336, wc @ +80216064;
  //        wob @ +0 after k_gate.
  //   dbuf fp16 exp(delta) sigma [25088,512] @ 205520896 (25.7 MB) — dead after gla3;
  //        wgb bf16 [1024,512] @ 205520896 written AFTER gla3 (1 MB)
  //   ebF/ebB fp16 @ 231211008 / 232013824
  // d_out (51.38 MB): xs @ 0 (25.69 MB, live until g-GEMM); dSf fp32 [3,256,64,128]
  //   @ 25690112 (25.17 MB, ends 50855936 <= 51380224 OK)
  if (ws_size < 232816640u) return;
  char* wsb = (char*)d_ws;
  char* dob = (char*)d_out;
  unsigned short* qkv  = (unsigned short*)(wsb + 0);
  unsigned short* g    = (unsigned short*)(wsb + 51380224);
  unsigned short* og   = (unsigned short*)(wsb + 102760448);
  float*          dSseg= (float*)(wsb + 102760448);
  unsigned short* zbuf = (unsigned short*)(wsb + 102760448 + 25690112);
  unsigned short* wqb  = (unsigned short*)(wsb + 102760448 + 77070336);
  unsigned short* wc   = (unsigned short*)(wsb + 102760448 + 80216064);
  unsigned short* dbuf = (unsigned short*)(wsb + 205520896);
  unsigned short* wgb  = (unsigned short*)(wsb + 205520896);   // overwrites dbuf AFTER gla3
  unsigned short* ebF  = (unsigned short*)(wsb + 231211008);
  unsigned short* ebB  = (unsigned short*)(wsb + 232013824);
  unsigned short* xs   = (unsigned short*)(dob + 0);
  float*          dSf  = (float*)(dob + 25690112);
  unsigned short* wob  = og;                         // after k_gate, og dead
  unsigned short* y    = qkv;                        // qkv dead after k_gla3
  float*          outp = (float*)d_out;

  k_conv_silu<<<NTOK*128/256, 256, 0, stream>>>(x, cw, xs);
  k_w2b<<<1024, 256, 0, stream>>>(qkvw, wqb, 2048*512);
  k_wc<<<2048, 256, 0, stream>>>(gkw1, gkw2, wc);
  k_gemm_mfma<0,1><<<dim3(16,196), 256, 0, stream>>>(xs, wqb, nullptr, qkv,  NTOK, 2048, 512);
  k_gemm_mfma<0,1><<<dim3(8,196),  256, 0, stream>>>(xs, wc,  gkb2,    zbuf, NTOK, 1024, 512);
  k_prep<<<BBATCH*NC2, 256, 0, stream>>>(qkv, zbuf, dbuf, ebF, ebB);
  k_gla_state<<<768, 256, 0, stream>>>(qkv, dbuf, ebF, ebB, dSseg);
  k_gla_comb<<<256, 256, 0, stream>>>(dSseg, dSf, ebF, ebB);
  k_gla3<<<512, 256, 0, stream>>>(qkv, dbuf, ebF, ebB, og, dSf);
  k_w2b<<<512,  256, 0, stream>>>(gw, wgb, 1024*512);                      // dbuf dead now
  k_gemm_mfma<1,1><<<dim3(8,196),  256, 0, stream>>>(xs, wgb, gb, g, NTOK, 1024, 512);
  k_gate<<<NTOK, 256, 0, stream>>>(og, g, gnw, lnw, y);
  k_w2b<<<512, 256, 0, stream>>>(ow, wob, 512*1024);
  k_gemm_mfma<0,0><<<dim3(4,196), 256, 0, stream>>>(y, wob, nullptr, outp, NTOK, 512, 1024);
}